// Round 8
// baseline (479.700 us; speedup 1.0000x reference)
//
#include <hip/hip_runtime.h>

typedef unsigned short u16;
typedef unsigned int u32;
typedef __attribute__((ext_vector_type(8))) short short8;
typedef __attribute__((ext_vector_type(8))) _Float16 half8;
typedef __attribute__((ext_vector_type(4))) float f32x4;

#define DEV __device__ __forceinline__

DEV void async_copy16(const void* g, void* l) {
  __builtin_amdgcn_global_load_lds((const __attribute__((address_space(1))) u32*)g,
                                   (__attribute__((address_space(3))) u32*)l, 16, 0, 0);
}
DEV float bf2f(u16 u) { return __uint_as_float(((u32)u) << 16); }
DEV u16 f2bf(float f) {
  u32 x = __float_as_uint(f);
  return (u16)((x + 0x7fffu + ((x >> 16) & 1u)) >> 16);
}
DEV u16 f2h_bits(float f) { _Float16 h = (_Float16)f; return __builtin_bit_cast(u16, h); }
DEV float h2f_bits(u16 b) { return (float)__builtin_bit_cast(_Float16, b); }
DEV float silu_f(float x) { return x / (1.0f + __expf(-x)); }

// Stage one 128x32 f16 tile (8KB) into LDS with XOR chunk pre-swizzle.
DEV void stage_tile(const u16* __restrict__ G, size_t grow_base, int k0, u16* L, int t) {
#pragma unroll
  for (int it = 0; it < 2; ++it) {
    int c = t + it * 256;
    int r = c >> 2, j = c & 3;
    int js = j ^ ((r >> 1) & 3);
    async_copy16(G + ((grow_base + (size_t)r) << 10) + k0 + js * 8,
                 (char*)L + (size_t)c * 16);
  }
}
DEV half8 frag(const u16* L, int rr, int lq) {
  int sw = lq ^ ((rr >> 1) & 3);
  return *(const half8*)((const char*)L + (size_t)rr * 64 + sw * 16);
}
DEV short8 frag_s(const u16* L, int rr, int lq) {
  int sw = lq ^ ((rr >> 1) & 3);
  return *(const short8*)((const char*)L + (size_t)rr * 64 + sw * 16);
}

// ---------------------------------------------------------------------------
// Transpose + convert: Wt[n][k] = bf16(W[k][n])   (for W_out)
// ---------------------------------------------------------------------------
__global__ __launch_bounds__(256) void transpose_k(const float* __restrict__ W,
                                                   u16* __restrict__ Wt,
                                                   int K, int N) {
  __shared__ float s[32][33];
  int t = threadIdx.x;
  int tx = t & 31, ty = t >> 5;
  int ntk = K >> 5;
  int bk = blockIdx.x % ntk, bn = blockIdx.x / ntk;
  int k0 = bk * 32, n0 = bn * 32;
#pragma unroll
  for (int i = 0; i < 4; ++i)
    s[ty + 8 * i][tx] = W[(size_t)(k0 + ty + 8 * i) * N + n0 + tx];
  __syncthreads();
#pragma unroll
  for (int i = 0; i < 4; ++i) {
    int r = ty + 8 * i;
    Wt[(size_t)(n0 + r) * K + k0 + tx] = f2bf(s[tx][r]);
  }
}

// ---------------------------------------------------------------------------
// Split x (f32) into f16 hi/lo planes: X0 = f16(x), X1 = f16((x - X0)*4096).
// ---------------------------------------------------------------------------
__global__ __launch_bounds__(256) void split_x(const float* __restrict__ x,
                                               u16* __restrict__ X0,
                                               u16* __restrict__ X1) {
  int i = (blockIdx.x * 256 + threadIdx.x) * 4;
  float4 v = *(const float4*)&x[i];
  ushort4 h0, h1;
  h0.x = f2h_bits(v.x); h1.x = f2h_bits((v.x - h2f_bits(h0.x)) * 4096.0f);
  h0.y = f2h_bits(v.y); h1.y = f2h_bits((v.y - h2f_bits(h0.y)) * 4096.0f);
  h0.z = f2h_bits(v.z); h1.z = f2h_bits((v.z - h2f_bits(h0.z)) * 4096.0f);
  h0.w = f2h_bits(v.w); h1.w = f2h_bits((v.w - h2f_bits(h0.w)) * 4096.0f);
  *(ushort4*)&X0[i] = h0;
  *(ushort4*)&X1[i] = h1;
}

// ---------------------------------------------------------------------------
// Split + transpose + COLUMN-PERMUTE W_qkv [1024][3072] -> planes [3072][1024].
// src col c -> (c%192)/64*1024 + (c/192)*64 + c%64 : Q cols in [0,1024),
// K in [1024,2048), V in [2048,3072).
// ---------------------------------------------------------------------------
__global__ __launch_bounds__(256) void split_w(const float* __restrict__ W,
                                               u16* __restrict__ W0t,
                                               u16* __restrict__ W1t) {
  __shared__ float s[32][33];
  int t = threadIdx.x;
  int tx = t & 31, ty = t >> 5;
  int bk = blockIdx.x & 31, bn = blockIdx.x >> 5;   // 32 k-tiles, 96 n-tiles
  int k0 = bk * 32, n0 = bn * 32;
#pragma unroll
  for (int i = 0; i < 4; ++i)
    s[ty + 8 * i][tx] = W[(size_t)(k0 + ty + 8 * i) * 3072 + n0 + tx];
  __syncthreads();
#pragma unroll
  for (int i = 0; i < 4; ++i) {
    int r = ty + 8 * i;
    int col = n0 + r;
    int h = col / 192, rem = col - h * 192;
    int cty = rem >> 6, d = rem & 63;
    int pcol = cty * 1024 + h * 64 + d;
    float v = s[tx][r];
    u16 h0 = f2h_bits(v);
    u16 h1 = f2h_bits((v - h2f_bits(h0)) * 4096.0f);
    size_t o = (size_t)pcol * 1024 + k0 + tx;
    W0t[o] = h0;
    W1t[o] = h1;
  }
}

// ---------------------------------------------------------------------------
// GEMM1a: Q/K columns, 3-pass split-f16 MFMA (f32-grade).
// Round-5 proven body + DOUBLE-BUFFER with ONE barrier per K-step:
//   barrier (drains prev stage's vmcnt + all reads of the buffer about to be
//   overwritten) -> issue stage into cur^1 -> ds_read + 48 MFMA from cur.
// The vmcnt(0) drain thus lands AFTER compute, overlapping staging with MFMA.
// LDS 64KB (2 blocks/CU, same as VGPR-limited occupancy), fused staging loop.
// Grid (16, 128): nb in [0,2048). Epilogue: silu -> Qf / Kf (f32).
// ---------------------------------------------------------------------------
__global__ __launch_bounds__(256, 2) void gemm_qk_f16(
    const u16* __restrict__ X0, const u16* __restrict__ X1,
    const u16* __restrict__ W0, const u16* __restrict__ W1,
    const float* __restrict__ bq,
    float* __restrict__ Qf, float* __restrict__ Kf) {
  __shared__ u16 lA0[2][128 * 32];
  __shared__ u16 lA1[2][128 * 32];
  __shared__ u16 lB0[2][128 * 32];
  __shared__ u16 lB1[2][128 * 32];   // 64KB
  int t = threadIdx.x;
  int w = t >> 6, l = t & 63;
  int wr = w >> 1, wc = w & 1;
  int lr = l & 15, lq = l >> 4;
  int mb = blockIdx.y * 128, nb = blockIdx.x * 128;
  int cty = nb >> 10;                 // 0=Q, 1=K
  f32x4 aM[4][4] = {};
  f32x4 aC[4][4] = {};

  // Prologue: stage k0=0 into buffer 0 (fused-address loop, round-5 shape).
#pragma unroll
  for (int it = 0; it < 2; ++it) {
    int c = t + it * 256;
    int r = c >> 2, j = c & 3;
    int js = j ^ ((r >> 1) & 3);
    size_t goA = (((size_t)(mb + r)) << 10) + js * 8;
    size_t goB = (((size_t)(nb + r)) << 10) + js * 8;
    async_copy16(X0 + goA, (char*)lA0[0] + (size_t)c * 16);
    async_copy16(X1 + goA, (char*)lA1[0] + (size_t)c * 16);
    async_copy16(W0 + goB, (char*)lB0[0] + (size_t)c * 16);
    async_copy16(W1 + goB, (char*)lB1[0] + (size_t)c * 16);
  }

  int cur = 0;
  for (int k0 = 0; k0 < 1024; k0 += 32) {
    __syncthreads();   // stage(cur) complete; all reads of cur^1 drained
    if (k0 + 32 < 1024) {
      int nxt = cur ^ 1;
#pragma unroll
      for (int it = 0; it < 2; ++it) {
        int c = t + it * 256;
        int r = c >> 2, j = c & 3;
        int js = j ^ ((r >> 1) & 3);
        size_t goA = (((size_t)(mb + r)) << 10) + (k0 + 32) + js * 8;
        size_t goB = (((size_t)(nb + r)) << 10) + (k0 + 32) + js * 8;
        async_copy16(X0 + goA, (char*)lA0[nxt] + (size_t)c * 16);
        async_copy16(X1 + goA, (char*)lA1[nxt] + (size_t)c * 16);
        async_copy16(W0 + goB, (char*)lB0[nxt] + (size_t)c * 16);
        async_copy16(W1 + goB, (char*)lB1[nxt] + (size_t)c * 16);
      }
    }
    half8 b0[4], b1[4];
#pragma unroll
    for (int nn = 0; nn < 4; ++nn) {
      int rr = wc * 64 + nn * 16 + lr;
      b0[nn] = frag(lB0[cur], rr, lq);
      b1[nn] = frag(lB1[cur], rr, lq);
    }
#pragma unroll
    for (int m = 0; m < 4; ++m) {
      int rr = wr * 64 + m * 16 + lr;
      half8 a0 = frag(lA0[cur], rr, lq);
      half8 a1 = frag(lA1[cur], rr, lq);
#pragma unroll
      for (int nn = 0; nn < 4; ++nn) {
        aM[m][nn] = __builtin_amdgcn_mfma_f32_16x16x32_f16(a0, b0[nn], aM[m][nn], 0, 0, 0);
        aC[m][nn] = __builtin_amdgcn_mfma_f32_16x16x32_f16(a0, b1[nn], aC[m][nn], 0, 0, 0);
        aC[m][nn] = __builtin_amdgcn_mfma_f32_16x16x32_f16(a1, b0[nn], aC[m][nn], 0, 0, 0);
      }
    }
    cur ^= 1;
  }

  const float cscale = 2.44140625e-4f;    // 1/4096
  float* dst = (cty == 0) ? Qf : Kf;
#pragma unroll
  for (int nn = 0; nn < 4; ++nn) {
    int col = nb + wc * 64 + nn * 16 + lr;
    int h = (col & 1023) >> 6, d0 = col & 63;
    float bias = bq[h * 192 + cty * 64 + d0];
#pragma unroll
    for (int m = 0; m < 4; ++m)
#pragma unroll
      for (int j = 0; j < 4; ++j) {
        int row = mb + wr * 64 + m * 16 + lq * 4 + j;
        int b = row >> 12, n = row & 4095;
        size_t base = (((size_t)(b * 16 + h) * 4096 + n) << 6) + d0;
        float val = aM[m][nn][j] + aC[m][nn][j] * cscale + bias;
        dst[base] = silu_f(val);
      }
  }
}

// ---------------------------------------------------------------------------
// GEMM1b: V columns, main plane only (bf16-grade output). 16KB LDS.
// Grid (8, 128): pnb = 2048 + blockIdx.x*128.
// ---------------------------------------------------------------------------
__global__ __launch_bounds__(256) void gemm_v_f16(
    const u16* __restrict__ X0, const u16* __restrict__ W0,
    const float* __restrict__ bq, u16* __restrict__ Vb) {
  __shared__ u16 lA0[128 * 32];
  __shared__ u16 lB0[128 * 32];   // 16KB
  int t = threadIdx.x;
  int w = t >> 6, l = t & 63;
  int wr = w >> 1, wc = w & 1;
  int lr = l & 15, lq = l >> 4;
  int mb = blockIdx.y * 128, nb = 2048 + blockIdx.x * 128;
  f32x4 aM[4][4] = {};

  for (int k0 = 0; k0 < 1024; k0 += 32) {
    stage_tile(X0, mb, k0, lA0, t);
    stage_tile(W0, nb, k0, lB0, t);
    __syncthreads();
    half8 b0[4];
#pragma unroll
    for (int nn = 0; nn < 4; ++nn) b0[nn] = frag(lB0, wc * 64 + nn * 16 + lr, lq);
#pragma unroll
    for (int m = 0; m < 4; ++m) {
      half8 a0 = frag(lA0, wr * 64 + m * 16 + lr, lq);
#pragma unroll
      for (int nn = 0; nn < 4; ++nn)
        aM[m][nn] = __builtin_amdgcn_mfma_f32_16x16x32_f16(a0, b0[nn], aM[m][nn], 0, 0, 0);
    }
    __syncthreads();
  }
#pragma unroll
  for (int nn = 0; nn < 4; ++nn) {
    int col = nb + wc * 64 + nn * 16 + lr;
    int h = (col & 1023) >> 6, d0 = col & 63;
    float bias = bq[h * 192 + 128 + d0];
#pragma unroll
    for (int m = 0; m < 4; ++m)
#pragma unroll
      for (int j = 0; j < 4; ++j) {
        int row = mb + wr * 64 + m * 16 + lq * 4 + j;
        int b = row >> 12, n = row & 4095;
        size_t base = (((size_t)(b * 16 + h) * 4096 + n) << 6) + d0;
        Vb[base] = f2bf(aM[m][nn][j] + bias);
      }
  }
}

// ---------------------------------------------------------------------------
// FALLBACK GEMM1 (f32 VALU) — used only if ws_size is too small for planes.
// ---------------------------------------------------------------------------
__global__ __launch_bounds__(256) void gemm_qkv(const float* __restrict__ X,
                                                const float* __restrict__ Wq,
                                                const float* __restrict__ bq,
                                                float* __restrict__ Qf,
                                                float* __restrict__ Kf,
                                                u16* __restrict__ Vb) {
  __shared__ float sA[16 * 132];
  __shared__ float sB[16 * 128];
  int t = threadIdx.x;
  int tm = t >> 4, tn = t & 15;
  int mb = blockIdx.y * 128, nb = blockIdx.x * 128;
  float acc[8][8] = {};

  for (int k0 = 0; k0 < 1024; k0 += 16) {
#pragma unroll
    for (int it = 0; it < 2; ++it) {
      int c = t + it * 256;
      int m = c >> 2, kc = (c & 3) * 4;
      float4 v = *(const float4*)&X[(size_t)(mb + m) * 1024 + k0 + kc];
      sA[(kc + 0) * 132 + m] = v.x;
      sA[(kc + 1) * 132 + m] = v.y;
      sA[(kc + 2) * 132 + m] = v.z;
      sA[(kc + 3) * 132 + m] = v.w;
      int kr = c >> 5, nc = (c & 31) * 4;
      async_copy16(&Wq[(size_t)(k0 + kr) * 3072 + nb + nc], (char*)sB + (size_t)c * 16);
    }
    __syncthreads();
#pragma unroll
    for (int k = 0; k < 16; ++k) {
      float4 a0 = *(const float4*)&sA[k * 132 + tm * 8];
      float4 a1 = *(const float4*)&sA[k * 132 + tm * 8 + 4];
      float4 b0 = *(const float4*)&sB[k * 128 + tn * 8];
      float4 b1 = *(const float4*)&sB[k * 128 + tn * 8 + 4];
      const float av[8] = {a0.x, a0.y, a0.z, a0.w, a1.x, a1.y, a1.z, a1.w};
      const float bv[8] = {b0.x, b0.y, b0.z, b0.w, b1.x, b1.y, b1.z, b1.w};
#pragma unroll
      for (int i = 0; i < 8; ++i)
#pragma unroll
        for (int j = 0; j < 8; ++j) acc[i][j] = fmaf(av[i], bv[j], acc[i][j]);
    }
    __syncthreads();
  }

  int c0 = nb + tn * 8;
  int h = c0 / 192, rem = c0 % 192;
  int ty = rem >> 6, d0 = rem & 63;
  float bb[8];
#pragma unroll
  for (int j = 0; j < 8; ++j) bb[j] = bq[c0 + j];
#pragma unroll
  for (int i = 0; i < 8; ++i) {
    int r = mb + tm * 8 + i;
    int b = r >> 12, n = r & 4095;
    size_t base = (((size_t)(b * 16 + h) * 4096 + n) << 6) + d0;
    if (ty == 2) {
      u16 pk[8];
#pragma unroll
      for (int j = 0; j < 8; ++j) pk[j] = f2bf(acc[i][j] + bb[j]);
      *(short8*)&Vb[base] = *(short8*)pk;
    } else {
      float* dst = (ty == 0) ? Qf : Kf;
#pragma unroll
      for (int j = 0; j < 8; ++j) dst[base + j] = silu_f(acc[i][j] + bb[j]);
    }
  }
}

// ---------------------------------------------------------------------------
// state partials: per (bh, chunk of 512 rows): P[d][e] = sum_n K[n][d]*V[n][e],
// plus ksum partial (fused from the LDS K tile).
// ---------------------------------------------------------------------------
__global__ __launch_bounds__(256) void state_partial(const float* __restrict__ Kf,
                                                     const u16* __restrict__ Vb,
                                                     float* __restrict__ stateP,
                                                     float* __restrict__ ksumP) {
  int bh = blockIdx.y, ch = blockIdx.x, t = threadIdx.x;
  __shared__ float sK[64 * 64];
  __shared__ u16 sV[64 * 64];
  __shared__ float sred[256];
  int n0 = ch * 512;
  size_t base = ((size_t)bh * 4096 + n0) << 6;
  float acc[4][4] = {};
  int te = t & 15, td = t >> 4;
  int kd = t & 63, kq = t >> 6;
  float kacc = 0.0f;

  for (int sc = 0; sc < 8; ++sc) {
    const float* gk = Kf + base + (size_t)sc * 64 * 64;
    const u16* gv = Vb + base + (size_t)sc * 64 * 64;
#pragma unroll
    for (int it = 0; it < 4; ++it)
      async_copy16(gk + (size_t)(t + it * 256) * 4, (char*)sK + (size_t)(t + it * 256) * 16);
#pragma unroll
    for (int it = 0; it < 2; ++it)
      async_copy16(gv + (size_t)(t + it * 256) * 8, (char*)sV + (size_t)(t + it * 256) * 16);
    __syncthreads();
#pragma unroll 4
    for (int n = 0; n < 64; ++n) {
      float4 k4 = *(const float4*)&sK[n * 64 + td * 4];
      const float ka[4] = {k4.x, k4.y, k4.z, k4.w};
      ushort4 vv = *(const ushort4*)&sV[n * 64 + te * 4];
      const float va[4] = {bf2f(vv.x), bf2f(vv.y), bf2f(vv.z), bf2f(vv.w)};
#pragma unroll
      for (int i = 0; i < 4; ++i)
#pragma unroll
        for (int j = 0; j < 4; ++j) acc[i][j] = fmaf(ka[i], va[j], acc[i][j]);
    }
#pragma unroll
    for (int i = 0; i < 16; ++i) kacc += sK[(kq * 16 + i) * 64 + kd];
    __syncthreads();
  }
  size_t pb = ((size_t)bh * 8 + ch) * 4096;
#pragma unroll
  for (int i = 0; i < 4; ++i)
#pragma unroll
    for (int j = 0; j < 4; ++j)
      stateP[pb + (size_t)(td * 4 + i) * 64 + te * 4 + j] = acc[i][j];

  sred[t] = kacc;
  __syncthreads();
  if (t < 64)
    ksumP[((size_t)bh * 8 + ch) * 64 + t] = sred[t] + sred[t + 64] + sred[t + 128] + sred[t + 192];
}

// ---------------------------------------------------------------------------
// reduce_state: collapse 8 partials -> final state (64x4096) and ksum (64x64).
// ---------------------------------------------------------------------------
__global__ __launch_bounds__(256) void reduce_state(const float* __restrict__ stateP,
                                                    const float* __restrict__ ksumP,
                                                    float* __restrict__ stateF,
                                                    float* __restrict__ ksumF) {
  int bh = blockIdx.x, t = threadIdx.x;
#pragma unroll
  for (int i = 0; i < 16; ++i) {
    int e = t + i * 256;
    float s = 0.0f;
#pragma unroll
    for (int c = 0; c < 8; ++c) s += stateP[((size_t)bh * 8 + c) * 4096 + e];
    stateF[(size_t)bh * 4096 + e] = s;
  }
  if (t < 64) {
    float s = 0.0f;
#pragma unroll
    for (int c = 0; c < 8; ++c) s += ksumP[((size_t)bh * 8 + c) * 64 + t];
    ksumF[(size_t)bh * 64 + t] = s;
  }
}

// ---------------------------------------------------------------------------
// attn_out: load final state/ksum into LDS; per row: num = q@state,
// den = q.ksum; out = num/(den+eps) -> bf16 row-major [B*N][1024].
// ---------------------------------------------------------------------------
__global__ __launch_bounds__(256) void attn_out(const float* __restrict__ Qf,
                                                const float* __restrict__ stateF,
                                                const float* __restrict__ ksumF,
                                                u16* __restrict__ outb) {
  int bh = blockIdx.y, chnk = blockIdx.x, t = threadIdx.x;
  __shared__ float sS[4096];
  __shared__ float sk[64];
#pragma unroll
  for (int i = 0; i < 16; ++i) {
    int e = t + i * 256;
    sS[e] = stateF[(size_t)bh * 4096 + e];
  }
  if (t < 64) sk[t] = ksumF[(size_t)bh * 64 + t];
  __syncthreads();

  int n = chnk * 256 + t;
  size_t qb = ((size_t)bh * 4096 + n) << 6;
  float4 a4[16] = {};
  float den = 0.0f;
#pragma unroll 4
  for (int dd = 0; dd < 16; ++dd) {
    float4 q4 = *(const float4*)&Qf[qb + dd * 4];
    const float qa[4] = {q4.x, q4.y, q4.z, q4.w};
#pragma unroll
    for (int jj = 0; jj < 4; ++jj) {
      int d = dd * 4 + jj;
      float qf = qa[jj];
      den = fmaf(qf, sk[d], den);
      const float4* srow = (const float4*)&sS[d * 64];
#pragma unroll
      for (int e4 = 0; e4 < 16; ++e4) {
        float4 s = srow[e4];
        a4[e4].x = fmaf(qf, s.x, a4[e4].x);
        a4[e4].y = fmaf(qf, s.y, a4[e4].y);
        a4[e4].z = fmaf(qf, s.z, a4[e4].z);
        a4[e4].w = fmaf(qf, s.w, a4[e4].w);
      }
    }
  }
  float rden = 1.0f / (den + 1e-6f);
  int b = bh >> 4, h = bh & 15;
  size_t ob = ((size_t)(b * 4096 + n) << 10) + h * 64;
#pragma unroll
  for (int e4 = 0; e4 < 16; ++e4) {
    ushort4 u;
    u.x = f2bf(a4[e4].x * rden);
    u.y = f2bf(a4[e4].y * rden);
    u.z = f2bf(a4[e4].z * rden);
    u.w = f2bf(a4[e4].w * rden);
    *(ushort4*)&outb[ob + e4 * 4] = u;
  }
}

// ---------------------------------------------------------------------------
// GEMM2 (bf16 MFMA): d_out = out_bf16 @ W_out + b_out.  M=16384,N=1024,K=1024.
// Single-buffer 2-barrier form, 16KB LDS.
// ---------------------------------------------------------------------------
__global__ __launch_bounds__(256) void gemm_out(const u16* __restrict__ A,
                                                const u16* __restrict__ Bt,
                                                const float* __restrict__ bias,
                                                float* __restrict__ C) {
  __shared__ u16 lA[128 * 32];
  __shared__ u16 lB[128 * 32];
  int t = threadIdx.x;
  int w = t >> 6, l = t & 63;
  int wr = w >> 1, wc = w & 1;
  int lr = l & 15, lq = l >> 4;
  int mb = blockIdx.y * 128, nb = blockIdx.x * 128;
  f32x4 acc[4][4] = {};

  for (int k0 = 0; k0 < 1024; k0 += 32) {
    stage_tile(A, mb, k0, lA, t);
    stage_tile(Bt, nb, k0, lB, t);
    __syncthreads();
    short8 af[4], bf[4];
#pragma unroll
    for (int m = 0; m < 4; ++m) af[m] = frag_s(lA, wr * 64 + m * 16 + lr, lq);
#pragma unroll
    for (int nn = 0; nn < 4; ++nn) bf[nn] = frag_s(lB, wc * 64 + nn * 16 + lr, lq);
#pragma unroll
    for (int m = 0; m < 4; ++m)
#pragma unroll
      for (int nn = 0; nn < 4; ++nn)
        acc[m][nn] = __builtin_amdgcn_mfma_f32_16x16x32_bf16(af[m], bf[nn], acc[m][nn], 0, 0, 0);
    __syncthreads();
  }

#pragma unroll
  for (int m = 0; m < 4; ++m)
#pragma unroll
    for (int nn = 0; nn < 4; ++nn) {
      int col = nb + wc * 64 + nn * 16 + lr;
      float bc = bias[col];
#pragma unroll
      for (int j = 0; j < 4; ++j) {
        int row = mb + wr * 64 + m * 16 + lq * 4 + j;
        C[((size_t)row << 10) + col] = acc[m][nn][j] + bc;
      }
    }
}

// ---------------------------------------------------------------------------
extern "C" void kernel_launch(void* const* d_in, const int* in_sizes, int n_in,
                              void* d_out, int out_size, void* d_ws, size_t ws_size,
                              hipStream_t stream) {
  const float* x    = (const float*)d_in[0];
  const float* Wqkv = (const float*)d_in[1];
  const float* bqkv = (const float*)d_in[2];
  const float* Wout = (const float*)d_in[3];
  const float* bout = (const float*)d_in[4];
  float* out = (float*)d_out;

  char* w = (char*)d_ws;
  const size_t offK  = 0;                      // K f32, 64MB (reused as out_bf16)
  const size_t offV  = offK + 67108864ULL;     // V bf16, 32MB
  const size_t offSP = offV + 33554432ULL;     // state partials f32, 8MB
  const size_t offKP = offSP + 8388608ULL;     // ksum partials, 128KB
  const size_t offWT = offKP + 131072ULL;      // WoutT bf16, 2MB
  const size_t offSF = offWT + 2097152ULL;     // state final f32, 1MB
  const size_t offKF = offSF + 1048576ULL;     // ksum final, 16KB
  const size_t need_base = offKF + 16384ULL;   // ~108MB
  const size_t offX0 = need_base;              // X hi f16, 32MB
  const size_t offX1 = offX0 + 33554432ULL;    // X lo f16, 32MB
  const size_t offW0 = offX1 + 33554432ULL;    // Wqkv hi f16 (T, permuted), 6MB
  const size_t offW1 = offW0 + 6291456ULL;     // Wqkv lo f16 (T, permuted), 6MB
  const size_t need_fast = offW1 + 6291456ULL; // ~184MB

  if (ws_size < need_base) return;

  float* Kf     = (float*)(w + offK);
  u16*   outb   = (u16*)(w + offK);
  u16*   Vb     = (u16*)(w + offV);
  float* stateP = (float*)(w + offSP);
  float* ksumP  = (float*)(w + offKP);
  u16*   WoutT  = (u16*)(w + offWT);
  float* stateF = (float*)(w + offSF);
  float* ksumF  = (float*)(w + offKF);
  float* Qf     = out;

  transpose_k<<<dim3(1024), dim3(256), 0, stream>>>(Wout, WoutT, 1024, 1024);

  if (ws_size >= need_fast) {
    u16* X0 = (u16*)(w + offX0);
    u16* X1 = (u16*)(w + offX1);
    u16* W0 = (u16*)(w + offW0);
    u16* W1 = (u16*)(w + offW1);
    split_x<<<dim3(16384), dim3(256), 0, stream>>>(x, X0, X1);
    split_w<<<dim3(3072), dim3(256), 0, stream>>>(Wqkv, W0, W1);
    gemm_qk_f16<<<dim3(16, 128), dim3(256), 0, stream>>>(X0, X1, W0, W1, bqkv, Qf, Kf);
    gemm_v_f16<<<dim3(8, 128), dim3(256), 0, stream>>>(X0, W0, bqkv, Vb);
  } else {
    gemm_qkv<<<dim3(24, 128), dim3(256), 0, stream>>>(x, Wqkv, bqkv, Qf, Kf, Vb);
  }

  state_partial<<<dim3(8, 64), dim3(256), 0, stream>>>(Kf, Vb, stateP, ksumP);
  reduce_state<<<dim3(64), dim3(256), 0, stream>>>(stateP, ksumP, stateF, ksumF);
  attn_out<<<dim3(16, 64), dim3(256), 0, stream>>>(Qf, stateF, ksumF, outb);
  gemm_out<<<dim3(8, 128), dim3(256), 0, stream>>>(outb, WoutT, bout, out);
}

// Round 9
// 433.045 us; speedup vs baseline: 1.1077x; 1.1077x over previous
//
#include <hip/hip_runtime.h>

typedef unsigned short u16;
typedef unsigned int u32;
typedef __attribute__((ext_vector_type(8))) short short8;
typedef __attribute__((ext_vector_type(8))) _Float16 half8;
typedef __attribute__((ext_vector_type(4))) float f32x4;

#define DEV __device__ __forceinline__

DEV void async_copy16(const void* g, void* l) {
  __builtin_amdgcn_global_load_lds((const __attribute__((address_space(1))) u32*)g,
                                   (__attribute__((address_space(3))) u32*)l, 16, 0, 0);
}
DEV float bf2f(u16 u) { return __uint_as_float(((u32)u) << 16); }
DEV u16 f2bf(float f) {
  u32 x = __float_as_uint(f);
  return (u16)((x + 0x7fffu + ((x >> 16) & 1u)) >> 16);
}
DEV u16 f2h_bits(float f) { _Float16 h = (_Float16)f; return __builtin_bit_cast(u16, h); }
DEV float h2f_bits(u16 b) { return (float)__builtin_bit_cast(_Float16, b); }
DEV float silu_f(float x) { return x / (1.0f + __expf(-x)); }

// Stage one 128x32 f16 tile (8KB) into LDS with XOR chunk pre-swizzle.
DEV void stage_tile(const u16* __restrict__ G, size_t grow_base, int k0, u16* L, int t) {
#pragma unroll
  for (int it = 0; it < 2; ++it) {
    int c = t + it * 256;
    int r = c >> 2, j = c & 3;
    int js = j ^ ((r >> 1) & 3);
    async_copy16(G + ((grow_base + (size_t)r) << 10) + k0 + js * 8,
                 (char*)L + (size_t)c * 16);
  }
}
DEV half8 frag(const u16* L, int rr, int lq) {
  int sw = lq ^ ((rr >> 1) & 3);
  return *(const half8*)((const char*)L + (size_t)rr * 64 + sw * 16);
}
DEV short8 frag_s(const u16* L, int rr, int lq) {
  int sw = lq ^ ((rr >> 1) & 3);
  return *(const short8*)((const char*)L + (size_t)rr * 64 + sw * 16);
}
// Fragment read from a [rows][64] f16 LDS tile (128B row stride), slot-swizzled.
DEV half8 frag64(const u16* L, int rr, int slot) {
  return *(const half8*)(L + (size_t)rr * 64 + ((slot ^ (rr & 7)) * 8));
}

// ---------------------------------------------------------------------------
// transpose_k (standalone, fallback path only): Wt[n][k] = bf16(W[k][n])
// ---------------------------------------------------------------------------
__global__ __launch_bounds__(256) void transpose_k(const float* __restrict__ W,
                                                   u16* __restrict__ Wt,
                                                   int K, int N) {
  __shared__ float s[32][33];
  int t = threadIdx.x;
  int tx = t & 31, ty = t >> 5;
  int ntk = K >> 5;
  int bk = blockIdx.x % ntk, bn = blockIdx.x / ntk;
  int k0 = bk * 32, n0 = bn * 32;
#pragma unroll
  for (int i = 0; i < 4; ++i)
    s[ty + 8 * i][tx] = W[(size_t)(k0 + ty + 8 * i) * N + n0 + tx];
  __syncthreads();
#pragma unroll
  for (int i = 0; i < 4; ++i) {
    int r = ty + 8 * i;
    Wt[(size_t)(n0 + r) * K + k0 + tx] = f2bf(s[tx][r]);
  }
}

// ---------------------------------------------------------------------------
// prep (fused): blocks [0,16384) split_x ; [16384,19456) split_w (transpose +
// column-permute + f16 split) ; [19456,20480) transpose W_out -> bf16.
// ---------------------------------------------------------------------------
__global__ __launch_bounds__(256) void prep(const float* __restrict__ x,
                                            u16* __restrict__ X0, u16* __restrict__ X1,
                                            const float* __restrict__ Wq,
                                            u16* __restrict__ W0t, u16* __restrict__ W1t,
                                            const float* __restrict__ Wo,
                                            u16* __restrict__ WoT) {
  __shared__ float s[32][33];
  int bid = blockIdx.x, t = threadIdx.x;
  if (bid < 16384) {
    int i = (bid * 256 + t) * 4;
    float4 v = *(const float4*)&x[i];
    ushort4 h0, h1;
    h0.x = f2h_bits(v.x); h1.x = f2h_bits((v.x - h2f_bits(h0.x)) * 4096.0f);
    h0.y = f2h_bits(v.y); h1.y = f2h_bits((v.y - h2f_bits(h0.y)) * 4096.0f);
    h0.z = f2h_bits(v.z); h1.z = f2h_bits((v.z - h2f_bits(h0.z)) * 4096.0f);
    h0.w = f2h_bits(v.w); h1.w = f2h_bits((v.w - h2f_bits(h0.w)) * 4096.0f);
    *(ushort4*)&X0[i] = h0;
    *(ushort4*)&X1[i] = h1;
  } else if (bid < 16384 + 3072) {
    int b2 = bid - 16384;
    int tx = t & 31, ty = t >> 5;
    int bk = b2 & 31, bn = b2 >> 5;
    int k0 = bk * 32, n0 = bn * 32;
#pragma unroll
    for (int i = 0; i < 4; ++i)
      s[ty + 8 * i][tx] = Wq[(size_t)(k0 + ty + 8 * i) * 3072 + n0 + tx];
    __syncthreads();
#pragma unroll
    for (int i = 0; i < 4; ++i) {
      int r = ty + 8 * i;
      int col = n0 + r;
      int h = col / 192, rem = col - h * 192;
      int cty = rem >> 6, d = rem & 63;
      int pcol = cty * 1024 + h * 64 + d;
      float v = s[tx][r];
      u16 h0 = f2h_bits(v);
      u16 h1 = f2h_bits((v - h2f_bits(h0)) * 4096.0f);
      size_t o = (size_t)pcol * 1024 + k0 + tx;
      W0t[o] = h0;
      W1t[o] = h1;
    }
  } else {
    int b3 = bid - 19456;
    int tx = t & 31, ty = t >> 5;
    int bk = b3 & 31, bn = b3 >> 5;
    int k0 = bk * 32, n0 = bn * 32;
#pragma unroll
    for (int i = 0; i < 4; ++i)
      s[ty + 8 * i][tx] = Wo[(size_t)(k0 + ty + 8 * i) * 1024 + n0 + tx];
    __syncthreads();
#pragma unroll
    for (int i = 0; i < 4; ++i) {
      int r = ty + 8 * i;
      WoT[(size_t)(n0 + r) * 1024 + k0 + tx] = f2bf(s[tx][r]);
    }
  }
}

// ---------------------------------------------------------------------------
// GEMM1a: Q/K columns, 3-pass split-f16 MFMA (f32-grade).
// EXACT round-7 proven shape: __launch_bounds__(256,2), fused staging loop,
// single-buffer 2-barrier, 32KB LDS, 104 VGPR, ~21% occ, ~896 TF.
// Grid (16, 128): nb in [0,2048). Epilogue: silu -> Qf / Kf (f32).
// ---------------------------------------------------------------------------
__global__ __launch_bounds__(256, 2) void gemm_qk_f16(
    const u16* __restrict__ X0, const u16* __restrict__ X1,
    const u16* __restrict__ W0, const u16* __restrict__ W1,
    const float* __restrict__ bq,
    float* __restrict__ Qf, float* __restrict__ Kf) {
  __shared__ u16 lA0[128 * 32];
  __shared__ u16 lA1[128 * 32];
  __shared__ u16 lB0[128 * 32];
  __shared__ u16 lB1[128 * 32];   // 32KB
  int t = threadIdx.x;
  int w = t >> 6, l = t & 63;
  int wr = w >> 1, wc = w & 1;
  int lr = l & 15, lq = l >> 4;
  int mb = blockIdx.y * 128, nb = blockIdx.x * 128;
  int cty = nb >> 10;                 // 0=Q, 1=K
  f32x4 aM[4][4] = {};
  f32x4 aC[4][4] = {};

  for (int k0 = 0; k0 < 1024; k0 += 32) {
#pragma unroll
    for (int it = 0; it < 2; ++it) {
      int c = t + it * 256;               // 16B chunk id, 0..511
      int r = c >> 2, j = c & 3;
      int js = j ^ ((r >> 1) & 3);        // source pre-swizzle (XOR involution)
      size_t goA = (((size_t)(mb + r)) << 10) + k0 + js * 8;
      size_t goB = (((size_t)(nb + r)) << 10) + k0 + js * 8;
      async_copy16(X0 + goA, (char*)lA0 + (size_t)c * 16);
      async_copy16(X1 + goA, (char*)lA1 + (size_t)c * 16);
      async_copy16(W0 + goB, (char*)lB0 + (size_t)c * 16);
      async_copy16(W1 + goB, (char*)lB1 + (size_t)c * 16);
    }
    __syncthreads();
    half8 b0[4], b1[4];
#pragma unroll
    for (int nn = 0; nn < 4; ++nn) {
      int rr = wc * 64 + nn * 16 + lr;
      b0[nn] = frag(lB0, rr, lq);
      b1[nn] = frag(lB1, rr, lq);
    }
#pragma unroll
    for (int m = 0; m < 4; ++m) {
      int rr = wr * 64 + m * 16 + lr;
      half8 a0 = frag(lA0, rr, lq);
      half8 a1 = frag(lA1, rr, lq);
#pragma unroll
      for (int nn = 0; nn < 4; ++nn) {
        aM[m][nn] = __builtin_amdgcn_mfma_f32_16x16x32_f16(a0, b0[nn], aM[m][nn], 0, 0, 0);
        aC[m][nn] = __builtin_amdgcn_mfma_f32_16x16x32_f16(a0, b1[nn], aC[m][nn], 0, 0, 0);
        aC[m][nn] = __builtin_amdgcn_mfma_f32_16x16x32_f16(a1, b0[nn], aC[m][nn], 0, 0, 0);
      }
    }
    __syncthreads();
  }

  const float cscale = 2.44140625e-4f;    // 1/4096
  float* dst = (cty == 0) ? Qf : Kf;
#pragma unroll
  for (int nn = 0; nn < 4; ++nn) {
    int col = nb + wc * 64 + nn * 16 + lr;
    int h = (col & 1023) >> 6, d0 = col & 63;
    float bias = bq[h * 192 + cty * 64 + d0];
#pragma unroll
    for (int m = 0; m < 4; ++m)
#pragma unroll
      for (int j = 0; j < 4; ++j) {
        int row = mb + wr * 64 + m * 16 + lq * 4 + j;
        int b = row >> 12, n = row & 4095;
        size_t base = (((size_t)(b * 16 + h) * 4096 + n) << 6) + d0;
        float val = aM[m][nn][j] + aC[m][nn][j] * cscale + bias;
        dst[base] = silu_f(val);
      }
  }
}

// ---------------------------------------------------------------------------
// GEMM1b: V columns, main plane only (bf16-grade output). 16KB LDS.
// Grid (8, 128): pnb = 2048 + blockIdx.x*128.
// ---------------------------------------------------------------------------
__global__ __launch_bounds__(256) void gemm_v_f16(
    const u16* __restrict__ X0, const u16* __restrict__ W0,
    const float* __restrict__ bq, u16* __restrict__ Vb) {
  __shared__ u16 lA0[128 * 32];
  __shared__ u16 lB0[128 * 32];   // 16KB
  int t = threadIdx.x;
  int w = t >> 6, l = t & 63;
  int wr = w >> 1, wc = w & 1;
  int lr = l & 15, lq = l >> 4;
  int mb = blockIdx.y * 128, nb = 2048 + blockIdx.x * 128;
  f32x4 aM[4][4] = {};

  for (int k0 = 0; k0 < 1024; k0 += 32) {
    stage_tile(X0, mb, k0, lA0, t);
    stage_tile(W0, nb, k0, lB0, t);
    __syncthreads();
    half8 b0[4];
#pragma unroll
    for (int nn = 0; nn < 4; ++nn) b0[nn] = frag(lB0, wc * 64 + nn * 16 + lr, lq);
#pragma unroll
    for (int m = 0; m < 4; ++m) {
      half8 a0 = frag(lA0, wr * 64 + m * 16 + lr, lq);
#pragma unroll
      for (int nn = 0; nn < 4; ++nn)
        aM[m][nn] = __builtin_amdgcn_mfma_f32_16x16x32_f16(a0, b0[nn], aM[m][nn], 0, 0, 0);
    }
    __syncthreads();
  }
#pragma unroll
  for (int nn = 0; nn < 4; ++nn) {
    int col = nb + wc * 64 + nn * 16 + lr;
    int h = (col & 1023) >> 6, d0 = col & 63;
    float bias = bq[h * 192 + 128 + d0];
#pragma unroll
    for (int m = 0; m < 4; ++m)
#pragma unroll
      for (int j = 0; j < 4; ++j) {
        int row = mb + wr * 64 + m * 16 + lq * 4 + j;
        int b = row >> 12, n = row & 4095;
        size_t base = (((size_t)(b * 16 + h) * 4096 + n) << 6) + d0;
        Vb[base] = f2bf(aM[m][nn][j] + bias);
      }
  }
}

// ---------------------------------------------------------------------------
// FALLBACK GEMM1 (f32 VALU) — used only if ws_size is too small for planes.
// ---------------------------------------------------------------------------
__global__ __launch_bounds__(256) void gemm_qkv(const float* __restrict__ X,
                                                const float* __restrict__ Wq,
                                                const float* __restrict__ bq,
                                                float* __restrict__ Qf,
                                                float* __restrict__ Kf,
                                                u16* __restrict__ Vb) {
  __shared__ float sA[16 * 132];
  __shared__ float sB[16 * 128];
  int t = threadIdx.x;
  int tm = t >> 4, tn = t & 15;
  int mb = blockIdx.y * 128, nb = blockIdx.x * 128;
  float acc[8][8] = {};

  for (int k0 = 0; k0 < 1024; k0 += 16) {
#pragma unroll
    for (int it = 0; it < 2; ++it) {
      int c = t + it * 256;
      int m = c >> 2, kc = (c & 3) * 4;
      float4 v = *(const float4*)&X[(size_t)(mb + m) * 1024 + k0 + kc];
      sA[(kc + 0) * 132 + m] = v.x;
      sA[(kc + 1) * 132 + m] = v.y;
      sA[(kc + 2) * 132 + m] = v.z;
      sA[(kc + 3) * 132 + m] = v.w;
      int kr = c >> 5, nc = (c & 31) * 4;
      async_copy16(&Wq[(size_t)(k0 + kr) * 3072 + nb + nc], (char*)sB + (size_t)c * 16);
    }
    __syncthreads();
#pragma unroll
    for (int k = 0; k < 16; ++k) {
      float4 a0 = *(const float4*)&sA[k * 132 + tm * 8];
      float4 a1 = *(const float4*)&sA[k * 132 + tm * 8 + 4];
      float4 b0 = *(const float4*)&sB[k * 128 + tn * 8];
      float4 b1 = *(const float4*)&sB[k * 128 + tn * 8 + 4];
      const float av[8] = {a0.x, a0.y, a0.z, a0.w, a1.x, a1.y, a1.z, a1.w};
      const float bv[8] = {b0.x, b0.y, b0.z, b0.w, b1.x, b1.y, b1.z, b1.w};
#pragma unroll
      for (int i = 0; i < 8; ++i)
#pragma unroll
        for (int j = 0; j < 8; ++j) acc[i][j] = fmaf(av[i], bv[j], acc[i][j]);
    }
    __syncthreads();
  }

  int c0 = nb + tn * 8;
  int h = c0 / 192, rem = c0 % 192;
  int ty = rem >> 6, d0 = rem & 63;
  float bb[8];
#pragma unroll
  for (int j = 0; j < 8; ++j) bb[j] = bq[c0 + j];
#pragma unroll
  for (int i = 0; i < 8; ++i) {
    int r = mb + tm * 8 + i;
    int b = r >> 12, n = r & 4095;
    size_t base = (((size_t)(b * 16 + h) * 4096 + n) << 6) + d0;
    if (ty == 2) {
      u16 pk[8];
#pragma unroll
      for (int j = 0; j < 8; ++j) pk[j] = f2bf(acc[i][j] + bb[j]);
      *(short8*)&Vb[base] = *(short8*)pk;
    } else {
      float* dst = (ty == 0) ? Qf : Kf;
#pragma unroll
      for (int j = 0; j < 8; ++j) dst[base + j] = silu_f(acc[i][j] + bb[j]);
    }
  }
}

// ---------------------------------------------------------------------------
// state partials: per (bh, chunk of 512 rows): P[d][e] = sum_n K[n][d]*V[n][e],
// plus ksum partial (fused from the LDS K tile).
// ---------------------------------------------------------------------------
__global__ __launch_bounds__(256) void state_partial(const float* __restrict__ Kf,
                                                     const u16* __restrict__ Vb,
                                                     float* __restrict__ stateP,
                                                     float* __restrict__ ksumP) {
  int bh = blockIdx.y, ch = blockIdx.x, t = threadIdx.x;
  __shared__ float sK[64 * 64];
  __shared__ u16 sV[64 * 64];
  __shared__ float sred[256];
  int n0 = ch * 512;
  size_t base = ((size_t)bh * 4096 + n0) << 6;
  float acc[4][4] = {};
  int te = t & 15, td = t >> 4;
  int kd = t & 63, kq = t >> 6;
  float kacc = 0.0f;

  for (int sc = 0; sc < 8; ++sc) {
    const float* gk = Kf + base + (size_t)sc * 64 * 64;
    const u16* gv = Vb + base + (size_t)sc * 64 * 64;
#pragma unroll
    for (int it = 0; it < 4; ++it)
      async_copy16(gk + (size_t)(t + it * 256) * 4, (char*)sK + (size_t)(t + it * 256) * 16);
#pragma unroll
    for (int it = 0; it < 2; ++it)
      async_copy16(gv + (size_t)(t + it * 256) * 8, (char*)sV + (size_t)(t + it * 256) * 16);
    __syncthreads();
#pragma unroll 4
    for (int n = 0; n < 64; ++n) {
      float4 k4 = *(const float4*)&sK[n * 64 + td * 4];
      const float ka[4] = {k4.x, k4.y, k4.z, k4.w};
      ushort4 vv = *(const ushort4*)&sV[n * 64 + te * 4];
      const float va[4] = {bf2f(vv.x), bf2f(vv.y), bf2f(vv.z), bf2f(vv.w)};
#pragma unroll
      for (int i = 0; i < 4; ++i)
#pragma unroll
        for (int j = 0; j < 4; ++j) acc[i][j] = fmaf(ka[i], va[j], acc[i][j]);
    }
#pragma unroll
    for (int i = 0; i < 16; ++i) kacc += sK[(kq * 16 + i) * 64 + kd];
    __syncthreads();
  }
  size_t pb = ((size_t)bh * 8 + ch) * 4096;
#pragma unroll
  for (int i = 0; i < 4; ++i)
#pragma unroll
    for (int j = 0; j < 4; ++j)
      stateP[pb + (size_t)(td * 4 + i) * 64 + te * 4 + j] = acc[i][j];

  sred[t] = kacc;
  __syncthreads();
  if (t < 64)
    ksumP[((size_t)bh * 8 + ch) * 64 + t] = sred[t] + sred[t + 64] + sred[t + 128] + sred[t + 192];
}

// ---------------------------------------------------------------------------
// reduce_state: collapse 8 partials -> stateT f16 [bh][e][d] + ksum f32.
// ---------------------------------------------------------------------------
__global__ __launch_bounds__(256) void reduce_state(const float* __restrict__ stateP,
                                                    const float* __restrict__ ksumP,
                                                    u16* __restrict__ sTh,
                                                    float* __restrict__ ksumF) {
  int bh = blockIdx.x, t = threadIdx.x;
#pragma unroll
  for (int i = 0; i < 16; ++i) {
    int idx = t + i * 256;             // idx = d*64 + e
    float s = 0.0f;
#pragma unroll
    for (int c = 0; c < 8; ++c) s += stateP[((size_t)bh * 8 + c) * 4096 + idx];
    int d = idx >> 6, e = idx & 63;
    sTh[((size_t)bh << 12) + e * 64 + d] = f2h_bits(s);
  }
  if (t < 64) {
    float s = 0.0f;
#pragma unroll
    for (int c = 0; c < 8; ++c) s += ksumP[((size_t)bh * 8 + c) * 64 + t];
    ksumF[(size_t)bh * 64 + t] = s;
  }
}

// ---------------------------------------------------------------------------
// attn_mfma: per (chunk of 256 rows, bh).  den = f32 VALU (from f32 Q during
// staging); num = q16 @ stateT via f16 MFMA.  out -> bf16 [B*N][1024].
// ---------------------------------------------------------------------------
__global__ __launch_bounds__(256) void attn_mfma(const float* __restrict__ Qf,
                                                 const u16* __restrict__ sTh,
                                                 const float* __restrict__ ksumF,
                                                 u16* __restrict__ outb) {
  __shared__ u16 q16[256 * 64];      // swizzled [row][64] f16, 32KB
  __shared__ u16 sT[64 * 64];        // swizzled [e][64] f16, 8KB
  __shared__ float denp[256 * 4];    // 4KB
  __shared__ float den[256];         // 1KB
  int bh = blockIdx.y, chnk = blockIdx.x, t = threadIdx.x;
  int w = t >> 6, l = t & 63;
  int lr16 = l & 15, lq4 = l >> 4;

  // stage stateT (8KB) with slot swizzle
  {
    const u16* src = sTh + ((size_t)bh << 12);
#pragma unroll
    for (int it = 0; it < 2; ++it) {
      int c = t + it * 256;            // 512 chunks of 8 u16
      short8 v = *(const short8*)(src + c * 8);
      int e = c >> 3, slot = c & 7;
      *(short8*)&sT[e * 64 + ((slot ^ (e & 7)) * 8)] = v;
    }
  }
  // stage q -> f16 (swizzled) + den partials; 4 threads per row, coalesced
  {
    int quarter = t & 3, rbase = t >> 2;
    float4 skr[4];
#pragma unroll
    for (int i4 = 0; i4 < 4; ++i4)
      skr[i4] = *(const float4*)&ksumF[(size_t)bh * 64 + quarter * 16 + i4 * 4];
#pragma unroll
    for (int p = 0; p < 4; ++p) {
      int row = rbase + p * 64;
      int n = chnk * 256 + row;
      const float* qrow = Qf + (((size_t)bh * 4096 + n) << 6) + quarter * 16;
      float dp = 0.0f;
      u16 h[16];
#pragma unroll
      for (int i4 = 0; i4 < 4; ++i4) {
        float4 v = *(const float4*)(qrow + i4 * 4);
        dp += v.x * skr[i4].x + v.y * skr[i4].y + v.z * skr[i4].z + v.w * skr[i4].w;
        h[i4 * 4 + 0] = f2h_bits(v.x);
        h[i4 * 4 + 1] = f2h_bits(v.y);
        h[i4 * 4 + 2] = f2h_bits(v.z);
        h[i4 * 4 + 3] = f2h_bits(v.w);
      }
      denp[row * 4 + quarter] = dp;
      int s0 = (quarter * 2) ^ (row & 7);
      int s1 = (quarter * 2 + 1) ^ (row & 7);
      *(short8*)&q16[row * 64 + s0 * 8] = *(short8*)&h[0];
      *(short8*)&q16[row * 64 + s1 * 8] = *(short8*)&h[8];
    }
  }
  __syncthreads();
  den[t] = denp[t * 4] + denp[t * 4 + 1] + denp[t * 4 + 2] + denp[t * 4 + 3];
  __syncthreads();

  // num via f16 MFMA: each wave does 64 rows x 64 e over K=64
  f32x4 acc[4][4] = {};
#pragma unroll
  for (int kh = 0; kh < 2; ++kh) {
    half8 bfr[4];
#pragma unroll
    for (int nt = 0; nt < 4; ++nt)
      bfr[nt] = frag64(sT, nt * 16 + lr16, kh * 4 + lq4);
#pragma unroll
    for (int rt = 0; rt < 4; ++rt) {
      half8 a = frag64(q16, w * 64 + rt * 16 + lr16, kh * 4 + lq4);
#pragma unroll
      for (int nt = 0; nt < 4; ++nt)
        acc[rt][nt] = __builtin_amdgcn_mfma_f32_16x16x32_f16(a, bfr[nt], acc[rt][nt], 0, 0, 0);
    }
  }

  int b = bh >> 4, hh = bh & 15;
#pragma unroll
  for (int rt = 0; rt < 4; ++rt) {
#pragma unroll
    for (int j = 0; j < 4; ++j) {
      int row = w * 64 + rt * 16 + lq4 * 4 + j;
      float rden = 1.0f / (den[row] + 1e-6f);
      int n = chnk * 256 + row;
      size_t ob = (((size_t)(b * 4096 + n)) << 10) + hh * 64;
#pragma unroll
      for (int nt = 0; nt < 4; ++nt) {
        int e = nt * 16 + lr16;
        outb[ob + e] = f2bf(acc[rt][nt][j] * rden);
      }
    }
  }
}

// ---------------------------------------------------------------------------
// GEMM2 (bf16 MFMA): d_out = out_bf16 @ W_out + b_out.  M=16384,N=1024,K=1024.
// Single-buffer 2-barrier form, 16KB LDS.
// ---------------------------------------------------------------------------
__global__ __launch_bounds__(256) void gemm_out(const u16* __restrict__ A,
                                                const u16* __restrict__ Bt,
                                                const float* __restrict__ bias,
                                                float* __restrict__ C) {
  __shared__ u16 lA[128 * 32];
  __shared__ u16 lB[128 * 32];
  int t = threadIdx.x;
  int w = t >> 6, l = t & 63;
  int wr = w >> 1, wc = w & 1;
  int lr = l & 15, lq = l >> 4;
  int mb = blockIdx.y * 128, nb = blockIdx.x * 128;
  f32x4 acc[4][4] = {};

  for (int k0 = 0; k0 < 1024; k0 += 32) {
    stage_tile(A, mb, k0, lA, t);
    stage_tile(Bt, nb, k0, lB, t);
    __syncthreads();
    short8 af[4], bf[4];
#pragma unroll
    for (int m = 0; m < 4; ++m) af[m] = frag_s(lA, wr * 64 + m * 16 + lr, lq);
#pragma unroll
    for (int nn = 0; nn < 4; ++nn) bf[nn] = frag_s(lB, wc * 64 + nn * 16 + lr, lq);
#pragma unroll
    for (int m = 0; m < 4; ++m)
#pragma unroll
      for (int nn = 0; nn < 4; ++nn)
        acc[m][nn] = __builtin_amdgcn_mfma_f32_16x16x32_bf16(af[m], bf[nn], acc[m][nn], 0, 0, 0);
    __syncthreads();
  }

#pragma unroll
  for (int m = 0; m < 4; ++m)
#pragma unroll
    for (int nn = 0; nn < 4; ++nn) {
      int col = nb + wc * 64 + nn * 16 + lr;
      float bc = bias[col];
#pragma unroll
      for (int j = 0; j < 4; ++j) {
        int row = mb + wr * 64 + m * 16 + lq * 4 + j;
        C[((size_t)row << 10) + col] = acc[m][nn][j] + bc;
      }
    }
}

// ---------------------------------------------------------------------------
extern "C" void kernel_launch(void* const* d_in, const int* in_sizes, int n_in,
                              void* d_out, int out_size, void* d_ws, size_t ws_size,
                              hipStream_t stream) {
  const float* x    = (const float*)d_in[0];
  const float* Wqkv = (const float*)d_in[1];
  const float* bqkv = (const float*)d_in[2];
  const float* Wout = (const float*)d_in[3];
  const float* bout = (const float*)d_in[4];
  float* out = (float*)d_out;

  char* w = (char*)d_ws;
  const size_t offK  = 0;                      // K f32, 64MB (reused as out_bf16)
  const size_t offV  = offK + 67108864ULL;     // V bf16, 32MB
  const size_t offSP = offV + 33554432ULL;     // state partials f32, 8MB
  const size_t offKP = offSP + 8388608ULL;     // ksum partials, 128KB
  const size_t offWT = offKP + 131072ULL;      // WoutT bf16, 2MB
  const size_t offST = offWT + 2097152ULL;     // stateT f16, 512KB
  const size_t offKF = offST + 524288ULL;      // ksum final, 16KB
  const size_t need_base = offKF + 16384ULL;   // ~108MB
  const size_t offX0 = need_base;              // X hi f16, 32MB
  const size_t offX1 = offX0 + 33554432ULL;    // X lo f16, 32MB
  const size_t offW0 = offX1 + 33554432ULL;    // Wqkv hi f16 (T, permuted), 6MB
  const size_t offW1 = offW0 + 6291456ULL;     // Wqkv lo f16 (T, permuted), 6MB
  const size_t need_fast = offW1 + 6291456ULL; // ~184MB

  if (ws_size < need_base) return;

  float* Kf     = (float*)(w + offK);
  u16*   outb   = (u16*)(w + offK);
  u16*   Vb     = (u16*)(w + offV);
  float* stateP = (float*)(w + offSP);
  float* ksumP  = (float*)(w + offKP);
  u16*   WoutT  = (u16*)(w + offWT);
  u16*   sTh    = (u16*)(w + offST);
  float* ksumF  = (float*)(w + offKF);
  float* Qf     = out;

  if (ws_size >= need_fast) {
    u16* X0 = (u16*)(w + offX0);
    u16* X1 = (u16*)(w + offX1);
    u16* W0 = (u16*)(w + offW0);
    u16* W1 = (u16*)(w + offW1);
    prep<<<dim3(20480), dim3(256), 0, stream>>>(x, X0, X1, Wqkv, W0, W1, Wout, WoutT);
    gemm_qk_f16<<<dim3(16, 128), dim3(256), 0, stream>>>(X0, X1, W0, W1, bqkv, Qf, Kf);
    gemm_v_f16<<<dim3(8, 128), dim3(256), 0, stream>>>(X0, W0, bqkv, Vb);
  } else {
    transpose_k<<<dim3(1024), dim3(256), 0, stream>>>(Wout, WoutT, 1024, 1024);
    gemm_qkv<<<dim3(24, 128), dim3(256), 0, stream>>>(x, Wqkv, bqkv, Qf, Kf, Vb);
  }

  state_partial<<<dim3(8, 64), dim3(256), 0, stream>>>(Kf, Vb, stateP, ksumP);
  reduce_state<<<dim3(64), dim3(256), 0, stream>>>(stateP, ksumP, sTh, ksumF);
  attn_mfma<<<dim3(16, 64), dim3(256), 0, stream>>>(Qf, sTh, ksumF, outb);
  gemm_out<<<dim3(8, 128), dim3(256), 0, stream>>>(outb, WoutT, bout, out);
}

// Round 10
// 396.427 us; speedup vs baseline: 1.2101x; 1.0924x over previous
//
#include <hip/hip_runtime.h>

typedef unsigned short u16;
typedef unsigned int u32;
typedef __attribute__((ext_vector_type(8))) short short8;
typedef __attribute__((ext_vector_type(8))) _Float16 half8;
typedef __attribute__((ext_vector_type(4))) float f32x4;

#define DEV __device__ __forceinline__

DEV void async_copy16(const void* g, void* l) {
  __builtin_amdgcn_global_load_lds((const __attribute__((address_space(1))) u32*)g,
                                   (__attribute__((address_space(3))) u32*)l, 16, 0, 0);
}
DEV float bf2f(u16 u) { return __uint_as_float(((u32)u) << 16); }
DEV u16 f2bf(float f) {
  u32 x = __float_as_uint(f);
  return (u16)((x + 0x7fffu + ((x >> 16) & 1u)) >> 16);
}
DEV u16 f2h_bits(float f) { _Float16 h = (_Float16)f; return __builtin_bit_cast(u16, h); }
DEV float h2f_bits(u16 b) { return (float)__builtin_bit_cast(_Float16, b); }
DEV float silu_f(float x) { return x / (1.0f + __expf(-x)); }

// Stage one 128x32 f16 tile (8KB) into LDS with XOR chunk pre-swizzle.
DEV void stage_tile(const u16* __restrict__ G, size_t grow_base, int k0, u16* L, int t) {
#pragma unroll
  for (int it = 0; it < 2; ++it) {
    int c = t + it * 256;
    int r = c >> 2, j = c & 3;
    int js = j ^ ((r >> 1) & 3);
    async_copy16(G + ((grow_base + (size_t)r) << 10) + k0 + js * 8,
                 (char*)L + (size_t)c * 16);
  }
}
DEV half8 frag(const u16* L, int rr, int lq) {
  int sw = lq ^ ((rr >> 1) & 3);
  return *(const half8*)((const char*)L + (size_t)rr * 64 + sw * 16);
}
DEV short8 frag_s(const u16* L, int rr, int lq) {
  int sw = lq ^ ((rr >> 1) & 3);
  return *(const short8*)((const char*)L + (size_t)rr * 64 + sw * 16);
}
// Fragment read from a [rows][64] f16 LDS tile (128B row stride), slot-swizzled.
DEV half8 frag64(const u16* L, int rr, int slot) {
  return *(const half8*)(L + (size_t)rr * 64 + ((slot ^ (rr & 7)) * 8));
}

// ---------------------------------------------------------------------------
// transpose_k (fallback path only): Wt[n][k] = bf16(W[k][n])
// ---------------------------------------------------------------------------
__global__ __launch_bounds__(256) void transpose_k(const float* __restrict__ W,
                                                   u16* __restrict__ Wt,
                                                   int K, int N) {
  __shared__ float s[32][33];
  int t = threadIdx.x;
  int tx = t & 31, ty = t >> 5;
  int ntk = K >> 5;
  int bk = blockIdx.x % ntk, bn = blockIdx.x / ntk;
  int k0 = bk * 32, n0 = bn * 32;
#pragma unroll
  for (int i = 0; i < 4; ++i)
    s[ty + 8 * i][tx] = W[(size_t)(k0 + ty + 8 * i) * N + n0 + tx];
  __syncthreads();
#pragma unroll
  for (int i = 0; i < 4; ++i) {
    int r = ty + 8 * i;
    Wt[(size_t)(n0 + r) * K + k0 + tx] = f2bf(s[tx][r]);
  }
}

// ---------------------------------------------------------------------------
// prep (fused): blocks [0,16384) split_x ; [16384,19456) split_w ;
// [19456,20480) transpose W_out -> bf16.
// ---------------------------------------------------------------------------
__global__ __launch_bounds__(256) void prep(const float* __restrict__ x,
                                            u16* __restrict__ X0, u16* __restrict__ X1,
                                            const float* __restrict__ Wq,
                                            u16* __restrict__ W0t, u16* __restrict__ W1t,
                                            const float* __restrict__ Wo,
                                            u16* __restrict__ WoT) {
  __shared__ float s[32][33];
  int bid = blockIdx.x, t = threadIdx.x;
  if (bid < 16384) {
    int i = (bid * 256 + t) * 4;
    float4 v = *(const float4*)&x[i];
    ushort4 h0, h1;
    h0.x = f2h_bits(v.x); h1.x = f2h_bits((v.x - h2f_bits(h0.x)) * 4096.0f);
    h0.y = f2h_bits(v.y); h1.y = f2h_bits((v.y - h2f_bits(h0.y)) * 4096.0f);
    h0.z = f2h_bits(v.z); h1.z = f2h_bits((v.z - h2f_bits(h0.z)) * 4096.0f);
    h0.w = f2h_bits(v.w); h1.w = f2h_bits((v.w - h2f_bits(h0.w)) * 4096.0f);
    *(ushort4*)&X0[i] = h0;
    *(ushort4*)&X1[i] = h1;
  } else if (bid < 16384 + 3072) {
    int b2 = bid - 16384;
    int tx = t & 31, ty = t >> 5;
    int bk = b2 & 31, bn = b2 >> 5;
    int k0 = bk * 32, n0 = bn * 32;
#pragma unroll
    for (int i = 0; i < 4; ++i)
      s[ty + 8 * i][tx] = Wq[(size_t)(k0 + ty + 8 * i) * 3072 + n0 + tx];
    __syncthreads();
#pragma unroll
    for (int i = 0; i < 4; ++i) {
      int r = ty + 8 * i;
      int col = n0 + r;
      int h = col / 192, rem = col - h * 192;
      int cty = rem >> 6, d = rem & 63;
      int pcol = cty * 1024 + h * 64 + d;
      float v = s[tx][r];
      u16 h0 = f2h_bits(v);
      u16 h1 = f2h_bits((v - h2f_bits(h0)) * 4096.0f);
      size_t o = (size_t)pcol * 1024 + k0 + tx;
      W0t[o] = h0;
      W1t[o] = h1;
    }
  } else {
    int b3 = bid - 19456;
    int tx = t & 31, ty = t >> 5;
    int bk = b3 & 31, bn = b3 >> 5;
    int k0 = bk * 32, n0 = bn * 32;
#pragma unroll
    for (int i = 0; i < 4; ++i)
      s[ty + 8 * i][tx] = Wo[(size_t)(k0 + ty + 8 * i) * 1024 + n0 + tx];
    __syncthreads();
#pragma unroll
    for (int i = 0; i < 4; ++i) {
      int r = ty + 8 * i;
      WoT[(size_t)(n0 + r) * 1024 + k0 + tx] = f2bf(s[tx][r]);
    }
  }
}

// ---------------------------------------------------------------------------
// GEMM1a: Q/K columns, 3-pass split-f16 MFMA (f32-grade).  Main loop = EXACT
// round-7/9 proven shape (launch_bounds(256,2), fused staging, 2 barriers,
// 32KB LDS).  Epilogue: Q -> silu f32 [bh][n][d]; K -> silu bf16 TRANSPOSED
// Kt[bh][d][n] + deterministic ksum partials (LDS-reduced, per row-tile).
// ---------------------------------------------------------------------------
__global__ __launch_bounds__(256, 2) void gemm_qk_f16(
    const u16* __restrict__ X0, const u16* __restrict__ X1,
    const u16* __restrict__ W0, const u16* __restrict__ W1,
    const float* __restrict__ bq,
    float* __restrict__ Qf, u16* __restrict__ Kt, float* __restrict__ ksumP2) {
  __shared__ u16 lA0[128 * 32];
  __shared__ u16 lA1[128 * 32];
  __shared__ u16 lB0[128 * 32];
  __shared__ u16 lB1[128 * 32];   // 32KB
  int t = threadIdx.x;
  int w = t >> 6, l = t & 63;
  int wr = w >> 1, wc = w & 1;
  int lr = l & 15, lq = l >> 4;
  int mb = blockIdx.y * 128, nb = blockIdx.x * 128;
  int cty = nb >> 10;                 // 0=Q, 1=K
  f32x4 aM[4][4] = {};
  f32x4 aC[4][4] = {};

  for (int k0 = 0; k0 < 1024; k0 += 32) {
#pragma unroll
    for (int it = 0; it < 2; ++it) {
      int c = t + it * 256;               // 16B chunk id, 0..511
      int r = c >> 2, j = c & 3;
      int js = j ^ ((r >> 1) & 3);        // source pre-swizzle (XOR involution)
      size_t goA = (((size_t)(mb + r)) << 10) + k0 + js * 8;
      size_t goB = (((size_t)(nb + r)) << 10) + k0 + js * 8;
      async_copy16(X0 + goA, (char*)lA0 + (size_t)c * 16);
      async_copy16(X1 + goA, (char*)lA1 + (size_t)c * 16);
      async_copy16(W0 + goB, (char*)lB0 + (size_t)c * 16);
      async_copy16(W1 + goB, (char*)lB1 + (size_t)c * 16);
    }
    __syncthreads();
    half8 b0[4], b1[4];
#pragma unroll
    for (int nn = 0; nn < 4; ++nn) {
      int rr = wc * 64 + nn * 16 + lr;
      b0[nn] = frag(lB0, rr, lq);
      b1[nn] = frag(lB1, rr, lq);
    }
#pragma unroll
    for (int m = 0; m < 4; ++m) {
      int rr = wr * 64 + m * 16 + lr;
      half8 a0 = frag(lA0, rr, lq);
      half8 a1 = frag(lA1, rr, lq);
#pragma unroll
      for (int nn = 0; nn < 4; ++nn) {
        aM[m][nn] = __builtin_amdgcn_mfma_f32_16x16x32_f16(a0, b0[nn], aM[m][nn], 0, 0, 0);
        aC[m][nn] = __builtin_amdgcn_mfma_f32_16x16x32_f16(a0, b1[nn], aC[m][nn], 0, 0, 0);
        aC[m][nn] = __builtin_amdgcn_mfma_f32_16x16x32_f16(a1, b0[nn], aC[m][nn], 0, 0, 0);
      }
    }
    __syncthreads();
  }

  const float cscale = 2.44140625e-4f;    // 1/4096
  if (cty == 0) {
    // ---- Q epilogue (unchanged round-9) ----
#pragma unroll
    for (int nn = 0; nn < 4; ++nn) {
      int col = nb + wc * 64 + nn * 16 + lr;
      int h = (col & 1023) >> 6, d0 = col & 63;
      float bias = bq[h * 192 + d0];
#pragma unroll
      for (int m = 0; m < 4; ++m)
#pragma unroll
        for (int j = 0; j < 4; ++j) {
          int row = mb + wr * 64 + m * 16 + lq * 4 + j;
          int b = row >> 12, n = row & 4095;
          size_t base = (((size_t)(b * 16 + h) * 4096 + n) << 6) + d0;
          float val = aM[m][nn][j] + aC[m][nn][j] * cscale + bias;
          Qf[base] = silu_f(val);
        }
    }
  } else {
    // ---- K epilogue: silu -> bf16 Kt[bh*64+d][n] + ksum partials ----
    float* red = (float*)lA0;             // 4KB reuse (post-barrier safe)
    int b = mb >> 12, nbase = mb & 4095;
#pragma unroll
    for (int nn = 0; nn < 4; ++nn) {
      int clocal = wc * 64 + nn * 16 + lr;      // 0..127
      int colk = (nb - 1024) + clocal;          // 0..1023
      int h = colk >> 6, d0 = colk & 63;
      float bias = bq[h * 192 + 64 + d0];
      size_t krow = (((size_t)(b * 16 + h) * 64 + d0) << 12) + nbase + wr * 64;
      float lsum = 0.0f;
#pragma unroll
      for (int m = 0; m < 4; ++m) {
        ushort4 pk;
        float v0 = silu_f(aM[m][nn][0] + aC[m][nn][0] * cscale + bias);
        float v1 = silu_f(aM[m][nn][1] + aC[m][nn][1] * cscale + bias);
        float v2 = silu_f(aM[m][nn][2] + aC[m][nn][2] * cscale + bias);
        float v3 = silu_f(aM[m][nn][3] + aC[m][nn][3] * cscale + bias);
        lsum += v0 + v1 + v2 + v3;
        pk.x = f2bf(v0); pk.y = f2bf(v1); pk.z = f2bf(v2); pk.w = f2bf(v3);
        *(ushort4*)&Kt[krow + m * 16 + lq * 4] = pk;
      }
      red[clocal * 8 + wr * 4 + lq] = lsum;
    }
    __syncthreads();
    if (t < 128) {
      float s = 0.0f;
#pragma unroll
      for (int c = 0; c < 8; ++c) s += red[t * 8 + c];
      int colk = (nb - 1024) + t;
      int h = colk >> 6, d0 = colk & 63;
      int rowtile = blockIdx.y & 31;
      ksumP2[(((size_t)(b * 16 + h) * 64 + d0) << 5) + rowtile] = s;
    }
  }
}

// ---------------------------------------------------------------------------
// GEMM1b: V columns, main plane only -> bf16 TRANSPOSED Vt[bh*64+e][n].
// Grid (8, 128): pnb = 2048 + blockIdx.x*128.  16KB LDS.
// ---------------------------------------------------------------------------
__global__ __launch_bounds__(256) void gemm_v_f16(
    const u16* __restrict__ X0, const u16* __restrict__ W0,
    const float* __restrict__ bq, u16* __restrict__ Vt) {
  __shared__ u16 lA0[128 * 32];
  __shared__ u16 lB0[128 * 32];   // 16KB
  int t = threadIdx.x;
  int w = t >> 6, l = t & 63;
  int wr = w >> 1, wc = w & 1;
  int lr = l & 15, lq = l >> 4;
  int mb = blockIdx.y * 128, nb = 2048 + blockIdx.x * 128;
  f32x4 aM[4][4] = {};

  for (int k0 = 0; k0 < 1024; k0 += 32) {
    stage_tile(X0, mb, k0, lA0, t);
    stage_tile(W0, nb, k0, lB0, t);
    __syncthreads();
    half8 b0[4];
#pragma unroll
    for (int nn = 0; nn < 4; ++nn) b0[nn] = frag(lB0, wc * 64 + nn * 16 + lr, lq);
#pragma unroll
    for (int m = 0; m < 4; ++m) {
      half8 a0 = frag(lA0, wr * 64 + m * 16 + lr, lq);
#pragma unroll
      for (int nn = 0; nn < 4; ++nn)
        aM[m][nn] = __builtin_amdgcn_mfma_f32_16x16x32_f16(a0, b0[nn], aM[m][nn], 0, 0, 0);
    }
    __syncthreads();
  }
  int b = mb >> 12, nbase = mb & 4095;
#pragma unroll
  for (int nn = 0; nn < 4; ++nn) {
    int colv = (nb - 2048) + wc * 64 + nn * 16 + lr;
    int h = colv >> 6, e0 = colv & 63;
    float bias = bq[h * 192 + 128 + e0];
    size_t vrow = (((size_t)(b * 16 + h) * 64 + e0) << 12) + nbase + wr * 64;
#pragma unroll
    for (int m = 0; m < 4; ++m) {
      ushort4 pk;
      pk.x = f2bf(aM[m][nn][0] + bias);
      pk.y = f2bf(aM[m][nn][1] + bias);
      pk.z = f2bf(aM[m][nn][2] + bias);
      pk.w = f2bf(aM[m][nn][3] + bias);
      *(ushort4*)&Vt[vrow + m * 16 + lq * 4] = pk;
    }
  }
}

// ---------------------------------------------------------------------------
// state_mfma: per (ch of 512 n, bh): stateP[d][e] partial = sum_n Kt[d][n]*Vt[e][n]
// via bf16 MFMA.  64x64 output, 4 waves (2x2 quadrants of 32x32), BK=32.
// ---------------------------------------------------------------------------
__global__ __launch_bounds__(256) void state_mfma(const u16* __restrict__ Kt,
                                                  const u16* __restrict__ Vt,
                                                  float* __restrict__ stateP) {
  __shared__ u16 sA[64 * 32];   // Kt rows d, 4KB
  __shared__ u16 sB[64 * 32];   // Vt rows e, 4KB
  int bh = blockIdx.y, ch = blockIdx.x, t = threadIdx.x;
  int w = t >> 6, l = t & 63;
  int wr = w >> 1, wc = w & 1;
  int lr = l & 15, lq = l >> 4;
  size_t rb = (size_t)bh << 6;           // row base (bh*64)
  f32x4 acc[2][2] = {};

  for (int n0 = ch * 512; n0 < ch * 512 + 512; n0 += 32) {
    {
      int c = t;                          // 256 chunks = whole 64x32 tile
      int r = c >> 2, j = c & 3;
      int js = j ^ ((r >> 1) & 3);
      size_t go = ((rb + (size_t)r) << 12) + n0 + js * 8;
      async_copy16(Kt + go, (char*)sA + (size_t)c * 16);
      async_copy16(Vt + go, (char*)sB + (size_t)c * 16);
    }
    __syncthreads();
    short8 bfr[2];
#pragma unroll
    for (int nn = 0; nn < 2; ++nn) bfr[nn] = frag_s(sB, wc * 32 + nn * 16 + lr, lq);
#pragma unroll
    for (int m = 0; m < 2; ++m) {
      short8 a = frag_s(sA, wr * 32 + m * 16 + lr, lq);
#pragma unroll
      for (int nn = 0; nn < 2; ++nn)
        acc[m][nn] = __builtin_amdgcn_mfma_f32_16x16x32_bf16(a, bfr[nn], acc[m][nn], 0, 0, 0);
    }
    __syncthreads();
  }

  size_t pb = ((size_t)bh * 8 + ch) * 4096;
#pragma unroll
  for (int m = 0; m < 2; ++m)
#pragma unroll
    for (int nn = 0; nn < 2; ++nn)
#pragma unroll
      for (int j = 0; j < 4; ++j) {
        int d = wr * 32 + m * 16 + lq * 4 + j;
        int e = wc * 32 + nn * 16 + lr;
        stateP[pb + (size_t)d * 64 + e] = acc[m][nn][j];
      }
}

// ---------------------------------------------------------------------------
// reduce_state2: 8 state partials -> stateT f16 [bh][e][d]; 32 ksum partials
// -> ksumF f32.
// ---------------------------------------------------------------------------
__global__ __launch_bounds__(256) void reduce_state2(const float* __restrict__ stateP,
                                                     const float* __restrict__ ksumP2,
                                                     u16* __restrict__ sTh,
                                                     float* __restrict__ ksumF) {
  int bh = blockIdx.x, t = threadIdx.x;
#pragma unroll
  for (int i = 0; i < 16; ++i) {
    int idx = t + i * 256;             // idx = d*64 + e
    float s = 0.0f;
#pragma unroll
    for (int c = 0; c < 8; ++c) s += stateP[((size_t)bh * 8 + c) * 4096 + idx];
    int d = idx >> 6, e = idx & 63;
    sTh[((size_t)bh << 12) + e * 64 + d] = f2h_bits(s);
  }
  if (t < 64) {
    float s = 0.0f;
#pragma unroll
    for (int c = 0; c < 32; ++c) s += ksumP2[(((size_t)bh * 64 + t) << 5) + c];
    ksumF[(size_t)bh * 64 + t] = s;
  }
}

// ---------------------------------------------------------------------------
// attn_mfma: den = f32 VALU (f32 Q); num = q16 @ stateT via f16 MFMA.
// out -> bf16 [B*N][1024].  (round-9 proven)
// ---------------------------------------------------------------------------
__global__ __launch_bounds__(256) void attn_mfma(const float* __restrict__ Qf,
                                                 const u16* __restrict__ sTh,
                                                 const float* __restrict__ ksumF,
                                                 u16* __restrict__ outb) {
  __shared__ u16 q16[256 * 64];
  __shared__ u16 sT[64 * 64];
  __shared__ float denp[256 * 4];
  __shared__ float den[256];
  int bh = blockIdx.y, chnk = blockIdx.x, t = threadIdx.x;
  int w = t >> 6, l = t & 63;
  int lr16 = l & 15, lq4 = l >> 4;

  {
    const u16* src = sTh + ((size_t)bh << 12);
#pragma unroll
    for (int it = 0; it < 2; ++it) {
      int c = t + it * 256;
      short8 v = *(const short8*)(src + c * 8);
      int e = c >> 3, slot = c & 7;
      *(short8*)&sT[e * 64 + ((slot ^ (e & 7)) * 8)] = v;
    }
  }
  {
    int quarter = t & 3, rbase = t >> 2;
    float4 skr[4];
#pragma unroll
    for (int i4 = 0; i4 < 4; ++i4)
      skr[i4] = *(const float4*)&ksumF[(size_t)bh * 64 + quarter * 16 + i4 * 4];
#pragma unroll
    for (int p = 0; p < 4; ++p) {
      int row = rbase + p * 64;
      int n = chnk * 256 + row;
      const float* qrow = Qf + (((size_t)bh * 4096 + n) << 6) + quarter * 16;
      float dp = 0.0f;
      u16 h[16];
#pragma unroll
      for (int i4 = 0; i4 < 4; ++i4) {
        float4 v = *(const float4*)(qrow + i4 * 4);
        dp += v.x * skr[i4].x + v.y * skr[i4].y + v.z * skr[i4].z + v.w * skr[i4].w;
        h[i4 * 4 + 0] = f2h_bits(v.x);
        h[i4 * 4 + 1] = f2h_bits(v.y);
        h[i4 * 4 + 2] = f2h_bits(v.z);
        h[i4 * 4 + 3] = f2h_bits(v.w);
      }
      denp[row * 4 + quarter] = dp;
      int s0 = (quarter * 2) ^ (row & 7);
      int s1 = (quarter * 2 + 1) ^ (row & 7);
      *(short8*)&q16[row * 64 + s0 * 8] = *(short8*)&h[0];
      *(short8*)&q16[row * 64 + s1 * 8] = *(short8*)&h[8];
    }
  }
  __syncthreads();
  den[t] = denp[t * 4] + denp[t * 4 + 1] + denp[t * 4 + 2] + denp[t * 4 + 3];
  __syncthreads();

  f32x4 acc[4][4] = {};
#pragma unroll
  for (int kh = 0; kh < 2; ++kh) {
    half8 bfr[4];
#pragma unroll
    for (int nt = 0; nt < 4; ++nt)
      bfr[nt] = frag64(sT, nt * 16 + lr16, kh * 4 + lq4);
#pragma unroll
    for (int rt = 0; rt < 4; ++rt) {
      half8 a = frag64(q16, w * 64 + rt * 16 + lr16, kh * 4 + lq4);
#pragma unroll
      for (int nt = 0; nt < 4; ++nt)
        acc[rt][nt] = __builtin_amdgcn_mfma_f32_16x16x32_f16(a, bfr[nt], acc[rt][nt], 0, 0, 0);
    }
  }

  int b = bh >> 4, hh = bh & 15;
#pragma unroll
  for (int rt = 0; rt < 4; ++rt) {
#pragma unroll
    for (int j = 0; j < 4; ++j) {
      int row = w * 64 + rt * 16 + lq4 * 4 + j;
      float rden = 1.0f / (den[row] + 1e-6f);
      int n = chnk * 256 + row;
      size_t ob = (((size_t)(b * 4096 + n)) << 10) + hh * 64;
#pragma unroll
      for (int nt = 0; nt < 4; ++nt) {
        int e = nt * 16 + lr16;
        outb[ob + e] = f2bf(acc[rt][nt][j] * rden);
      }
    }
  }
}

// ---------------------------------------------------------------------------
// GEMM2 (bf16 MFMA): d_out = out_bf16 @ W_out + b_out.  16KB LDS.
// ---------------------------------------------------------------------------
__global__ __launch_bounds__(256) void gemm_out(const u16* __restrict__ A,
                                                const u16* __restrict__ Bt,
                                                const float* __restrict__ bias,
                                                float* __restrict__ C) {
  __shared__ u16 lA[128 * 32];
  __shared__ u16 lB[128 * 32];
  int t = threadIdx.x;
  int w = t >> 6, l = t & 63;
  int wr = w >> 1, wc = w & 1;
  int lr = l & 15, lq = l >> 4;
  int mb = blockIdx.y * 128, nb = blockIdx.x * 128;
  f32x4 acc[4][4] = {};

  for (int k0 = 0; k0 < 1024; k0 += 32) {
    stage_tile(A, mb, k0, lA, t);
    stage_tile(Bt, nb, k0, lB, t);
    __syncthreads();
    short8 af[4], bf[4];
#pragma unroll
    for (int m = 0; m < 4; ++m) af[m] = frag_s(lA, wr * 64 + m * 16 + lr, lq);
#pragma unroll
    for (int nn = 0; nn < 4; ++nn) bf[nn] = frag_s(lB, wc * 64 + nn * 16 + lr, lq);
#pragma unroll
    for (int m = 0; m < 4; ++m)
#pragma unroll
      for (int nn = 0; nn < 4; ++nn)
        acc[m][nn] = __builtin_amdgcn_mfma_f32_16x16x32_bf16(af[m], bf[nn], acc[m][nn], 0, 0, 0);
    __syncthreads();
  }

#pragma unroll
  for (int m = 0; m < 4; ++m)
#pragma unroll
    for (int nn = 0; nn < 4; ++nn) {
      int col = nb + wc * 64 + nn * 16 + lr;
      float bc = bias[col];
#pragma unroll
      for (int j = 0; j < 4; ++j) {
        int row = mb + wr * 64 + m * 16 + lq * 4 + j;
        C[((size_t)row << 10) + col] = acc[m][nn][j] + bc;
      }
    }
}

// ---------------------------------------------------------------------------
// FALLBACK kernels (f32 VALU path, only if ws too small) — round-9 proven.
// ---------------------------------------------------------------------------
__global__ __launch_bounds__(256) void gemm_qkv(const float* __restrict__ X,
                                                const float* __restrict__ Wq,
                                                const float* __restrict__ bq,
                                                float* __restrict__ Qf,
                                                float* __restrict__ Kf,
                                                u16* __restrict__ Vb) {
  __shared__ float sA[16 * 132];
  __shared__ float sB[16 * 128];
  int t = threadIdx.x;
  int tm = t >> 4, tn = t & 15;
  int mb = blockIdx.y * 128, nb = blockIdx.x * 128;
  float acc[8][8] = {};

  for (int k0 = 0; k0 < 1024; k0 += 16) {
#pragma unroll
    for (int it = 0; it < 2; ++it) {
      int c = t + it * 256;
      int m = c >> 2, kc = (c & 3) * 4;
      float4 v = *(const float4*)&X[(size_t)(mb + m) * 1024 + k0 + kc];
      sA[(kc + 0) * 132 + m] = v.x;
      sA[(kc + 1) * 132 + m] = v.y;
      sA[(kc + 2) * 132 + m] = v.z;
      sA[(kc + 3) * 132 + m] = v.w;
      int kr = c >> 5, nc = (c & 31) * 4;
      async_copy16(&Wq[(size_t)(k0 + kr) * 3072 + nb + nc], (char*)sB + (size_t)c * 16);
    }
    __syncthreads();
#pragma unroll
    for (int k = 0; k < 16; ++k) {
      float4 a0 = *(const float4*)&sA[k * 132 + tm * 8];
      float4 a1 = *(const float4*)&sA[k * 132 + tm * 8 + 4];
      float4 b0 = *(const float4*)&sB[k * 128 + tn * 8];
      float4 b1 = *(const float4*)&sB[k * 128 + tn * 8 + 4];
      const float av[8] = {a0.x, a0.y, a0.z, a0.w, a1.x, a1.y, a1.z, a1.w};
      const float bv[8] = {b0.x, b0.y, b0.z, b0.w, b1.x, b1.y, b1.z, b1.w};
#pragma unroll
      for (int i = 0; i < 8; ++i)
#pragma unroll
        for (int j = 0; j < 8; ++j) acc[i][j] = fmaf(av[i], bv[j], acc[i][j]);
    }
    __syncthreads();
  }

  int c0 = nb + tn * 8;
  int h = c0 / 192, rem = c0 % 192;
  int ty = rem >> 6, d0 = rem & 63;
  float bb[8];
#pragma unroll
  for (int j = 0; j < 8; ++j) bb[j] = bq[c0 + j];
#pragma unroll
  for (int i = 0; i < 8; ++i) {
    int r = mb + tm * 8 + i;
    int b = r >> 12, n = r & 4095;
    size_t base = (((size_t)(b * 16 + h) * 4096 + n) << 6) + d0;
    if (ty == 2) {
      u16 pk[8];
#pragma unroll
      for (int j = 0; j < 8; ++j) pk[j] = f2bf(acc[i][j] + bb[j]);
      *(short8*)&Vb[base] = *(short8*)pk;
    } else {
      float* dst = (ty == 0) ? Qf : Kf;
#pragma unroll
      for (int j = 0; j < 8; ++j) dst[base + j] = silu_f(acc[i][j] + bb[j]);
    }
  }
}

__global__ __launch_bounds__(256) void state_partial(const float* __restrict__ Kf,
                                                     const u16* __restrict__ Vb,
                                                     float* __restrict__ stateP,
                                                     float* __restrict__ ksumP) {
  int bh = blockIdx.y, ch = blockIdx.x, t = threadIdx.x;
  __shared__ float sK[64 * 64];
  __shared__ u16 sV[64 * 64];
  __shared__ float sred[256];
  int n0 = ch * 512;
  size_t base = ((size_t)bh * 4096 + n0) << 6;
  float acc[4][4] = {};
  int te = t & 15, td = t >> 4;
  int kd = t & 63, kq = t >> 6;
  float kacc = 0.0f;

  for (int sc = 0; sc < 8; ++sc) {
    const float* gk = Kf + base + (size_t)sc * 64 * 64;
    const u16* gv = Vb + base + (size_t)sc * 64 * 64;
#pragma unroll
    for (int it = 0; it < 4; ++it)
      async_copy16(gk + (size_t)(t + it * 256) * 4, (char*)sK + (size_t)(t + it * 256) * 16);
#pragma unroll
    for (int it = 0; it < 2; ++it)
      async_copy16(gv + (size_t)(t + it * 256) * 8, (char*)sV + (size_t)(t + it * 256) * 16);
    __syncthreads();
#pragma unroll 4
    for (int n = 0; n < 64; ++n) {
      float4 k4 = *(const float4*)&sK[n * 64 + td * 4];
      const float ka[4] = {k4.x, k4.y, k4.z, k4.w};
      ushort4 vv = *(const ushort4*)&sV[n * 64 + te * 4];
      const float va[4] = {bf2f(vv.x), bf2f(vv.y), bf2f(vv.z), bf2f(vv.w)};
#pragma unroll
      for (int i = 0; i < 4; ++i)
#pragma unroll
        for (int j = 0; j < 4; ++j) acc[i][j] = fmaf(ka[i], va[j], acc[i][j]);
    }
#pragma unroll
    for (int i = 0; i < 16; ++i) kacc += sK[(kq * 16 + i) * 64 + kd];
    __syncthreads();
  }
  size_t pb = ((size_t)bh * 8 + ch) * 4096;
#pragma unroll
  for (int i = 0; i < 4; ++i)
#pragma unroll
    for (int j = 0; j < 4; ++j)
      stateP[pb + (size_t)(td * 4 + i) * 64 + te * 4 + j] = acc[i][j];

  sred[t] = kacc;
  __syncthreads();
  if (t < 64)
    ksumP[((size_t)bh * 8 + ch) * 64 + t] = sred[t] + sred[t + 64] + sred[t + 128] + sred[t + 192];
}

__global__ __launch_bounds__(256) void reduce_state_fb(const float* __restrict__ stateP,
                                                       const float* __restrict__ ksumP,
                                                       u16* __restrict__ sTh,
                                                       float* __restrict__ ksumF) {
  int bh = blockIdx.x, t = threadIdx.x;
#pragma unroll
  for (int i = 0; i < 16; ++i) {
    int idx = t + i * 256;
    float s = 0.0f;
#pragma unroll
    for (int c = 0; c < 8; ++c) s += stateP[((size_t)bh * 8 + c) * 4096 + idx];
    int d = idx >> 6, e = idx & 63;
    sTh[((size_t)bh << 12) + e * 64 + d] = f2h_bits(s);
  }
  if (t < 64) {
    float s = 0.0f;
#pragma unroll
    for (int c = 0; c < 8; ++c) s += ksumP[((size_t)bh * 8 + c) * 64 + t];
    ksumF[(size_t)bh * 64 + t] = s;
  }
}

// ---------------------------------------------------------------------------
extern "C" void kernel_launch(void* const* d_in, const int* in_sizes, int n_in,
                              void* d_out, int out_size, void* d_ws, size_t ws_size,
                              hipStream_t stream) {
  const float* x    = (const float*)d_in[0];
  const float* Wqkv = (const float*)d_in[1];
  const float* bqkv = (const float*)d_in[2];
  const float* Wout = (const float*)d_in[3];
  const float* bout = (const float*)d_in[4];
  float* out = (float*)d_out;

  char* w = (char*)d_ws;

  // ---- fast-path layout (~152MB) ----
  const size_t fKT  = 0;                        // Kt bf16 32MB (outb overlay)
  const size_t fVT  = fKT  + 33554432ULL;       // Vt bf16 32MB
  const size_t fSP  = fVT  + 33554432ULL;       // stateP f32 8MB
  const size_t fKP2 = fSP  + 8388608ULL;        // ksumP2 512KB
  const size_t fWT  = fKP2 + 524288ULL;         // WoutT bf16 2MB
  const size_t fST  = fWT  + 2097152ULL;        // sTh f16 512KB
  const size_t fKF  = fST  + 524288ULL;         // ksumF 16KB
  const size_t fX0  = fKF  + 16384ULL;          // X hi f16 32MB
  const size_t fX1  = fX0  + 33554432ULL;       // X lo f16 32MB
  const size_t fW0  = fX1  + 33554432ULL;       // Wqkv hi (T, permuted) 6MB
  const size_t fW1  = fW0  + 6291456ULL;        // Wqkv lo (T, permuted) 6MB
  const size_t need_fast = fW1 + 6291456ULL;    // ~152MB

  // ---- fallback layout (~108MB, round-9 proven) ----
  const size_t bK  = 0;                         // Kf f32 64MB (outb overlay)
  const size_t bV  = bK + 67108864ULL;
  const size_t bSP = bV + 33554432ULL;
  const size_t bKP = bSP + 8388608ULL;
  const size_t bWT = bKP + 131072ULL;
  const size_t bST = bWT + 2097152ULL;
  const size_t bKF = bST + 524288ULL;
  const size_t need_base = bKF + 16384ULL;

  if (ws_size >= need_fast) {
    u16*   Kt     = (u16*)(w + fKT);
    u16*   outb   = (u16*)(w + fKT);            // overlay after Kt consumed
    u16*   Vt     = (u16*)(w + fVT);
    float* stateP = (float*)(w + fSP);
    float* ksumP2 = (float*)(w + fKP2);
    u16*   WoutT  = (u16*)(w + fWT);
    u16*   sTh    = (u16*)(w + fST);
    float* ksumF  = (float*)(w + fKF);
    u16*   X0     = (u16*)(w + fX0);
    u16*   X1     = (u16*)(w + fX1);
    u16*   W0     = (u16*)(w + fW0);
    u16*   W1     = (u16*)(w + fW1);
    float* Qf     = out;

    prep<<<dim3(20480), dim3(256), 0, stream>>>(x, X0, X1, Wqkv, W0, W1, Wout, WoutT);
    gemm_qk_f16<<<dim3(16, 128), dim3(256), 0, stream>>>(X0, X1, W0, W1, bqkv, Qf, Kt, ksumP2);
    gemm_v_f16<<<dim3(8, 128), dim3(256), 0, stream>>>(X0, W0, bqkv, Vt);
    state_mfma<<<dim3(8, 64), dim3(256), 0, stream>>>(Kt, Vt, stateP);
    reduce_state2<<<dim3(64), dim3(256), 0, stream>>>(stateP, ksumP2, sTh, ksumF);
    attn_mfma<<<dim3(16, 64), dim3(256), 0, stream>>>(Qf, sTh, ksumF, outb);
    gemm_out<<<dim3(8, 128), dim3(256), 0, stream>>>(outb, WoutT, bout, out);
  } else if (ws_size >= need_base) {
    float* Kf     = (float*)(w + bK);
    u16*   outb   = (u16*)(w + bK);
    u16*   Vb     = (u16*)(w + bV);
    float* stateP = (float*)(w + bSP);
    float* ksumP  = (float*)(w + bKP);
    u16*   WoutT  = (u16*)(w + bWT);
    u16*   sTh    = (u16*)(w + bST);
    float* ksumF  = (float*)(w + bKF);
    float* Qf     = out;

    transpose_k<<<dim3(1024), dim3(256), 0, stream>>>(Wout, WoutT, 1024, 1024);
    gemm_qkv<<<dim3(24, 128), dim3(256), 0, stream>>>(x, Wqkv, bqkv, Qf, Kf, Vb);
    state_partial<<<dim3(8, 64), dim3(256), 0, stream>>>(Kf, Vb, stateP, ksumP);
    reduce_state_fb<<<dim3(64), dim3(256), 0, stream>>>(stateP, ksumP, sTh, ksumF);
    attn_mfma<<<dim3(16, 64), dim3(256), 0, stream>>>(Qf, sTh, ksumF, outb);
    gemm_out<<<dim3(8, 128), dim3(256), 0, stream>>>(outb, WoutT, bout, out);
  }
}

// Round 11
// 395.431 us; speedup vs baseline: 1.2131x; 1.0025x over previous
//
#include <hip/hip_runtime.h>

typedef unsigned short u16;
typedef unsigned int u32;
typedef __attribute__((ext_vector_type(8))) short short8;
typedef __attribute__((ext_vector_type(8))) _Float16 half8;
typedef __attribute__((ext_vector_type(4))) float f32x4;

#define DEV __device__ __forceinline__

DEV void async_copy16(const void* g, void* l) {
  __builtin_amdgcn_global_load_lds((const __attribute__((address_space(1))) u32*)g,
                                   (__attribute__((address_space(3))) u32*)l, 16, 0, 0);
}
DEV float bf2f(u16 u) { return __uint_as_float(((u32)u) << 16); }
DEV u16 f2bf(float f) {
  u32 x = __float_as_uint(f);
  return (u16)((x + 0x7fffu + ((x >> 16) & 1u)) >> 16);
}
DEV u16 f2h_bits(float f) { _Float16 h = (_Float16)f; return __builtin_bit_cast(u16, h); }
DEV float h2f_bits(u16 b) { return (float)__builtin_bit_cast(_Float16, b); }
DEV float silu_f(float x) { return x / (1.0f + __expf(-x)); }

// Stage one 128x32 f16 tile (8KB) into LDS with XOR chunk pre-swizzle.
DEV void stage_tile(const u16* __restrict__ G, size_t grow_base, int k0, u16* L, int t) {
#pragma unroll
  for (int it = 0; it < 2; ++it) {
    int c = t + it * 256;
    int r = c >> 2, j = c & 3;
    int js = j ^ ((r >> 1) & 3);
    async_copy16(G + ((grow_base + (size_t)r) << 10) + k0 + js * 8,
                 (char*)L + (size_t)c * 16);
  }
}
DEV half8 frag(const u16* L, int rr, int lq) {
  int sw = lq ^ ((rr >> 1) & 3);
  return *(const half8*)((const char*)L + (size_t)rr * 64 + sw * 16);
}
DEV short8 frag_s(const u16* L, int rr, int lq) {
  int sw = lq ^ ((rr >> 1) & 3);
  return *(const short8*)((const char*)L + (size_t)rr * 64 + sw * 16);
}
// Fragment read from a [rows][64] f16 LDS tile (128B row stride), slot-swizzled.
DEV half8 frag64(const u16* L, int rr, int slot) {
  return *(const half8*)(L + (size_t)rr * 64 + ((slot ^ (rr & 7)) * 8));
}

// ---------------------------------------------------------------------------
// transpose_k (fallback path only): Wt[n][k] = bf16(W[k][n])
// ---------------------------------------------------------------------------
__global__ __launch_bounds__(256) void transpose_k(const float* __restrict__ W,
                                                   u16* __restrict__ Wt,
                                                   int K, int N) {
  __shared__ float s[32][33];
  int t = threadIdx.x;
  int tx = t & 31, ty = t >> 5;
  int ntk = K >> 5;
  int bk = blockIdx.x % ntk, bn = blockIdx.x / ntk;
  int k0 = bk * 32, n0 = bn * 32;
#pragma unroll
  for (int i = 0; i < 4; ++i)
    s[ty + 8 * i][tx] = W[(size_t)(k0 + ty + 8 * i) * N + n0 + tx];
  __syncthreads();
#pragma unroll
  for (int i = 0; i < 4; ++i) {
    int r = ty + 8 * i;
    Wt[(size_t)(n0 + r) * K + k0 + tx] = f2bf(s[tx][r]);
  }
}

// ---------------------------------------------------------------------------
// prep (fused): blocks [0,16384) split_x ; [16384,19456) split_w ;
// [19456,20480) transpose W_out -> bf16.
// ---------------------------------------------------------------------------
__global__ __launch_bounds__(256) void prep(const float* __restrict__ x,
                                            u16* __restrict__ X0, u16* __restrict__ X1,
                                            const float* __restrict__ Wq,
                                            u16* __restrict__ W0t, u16* __restrict__ W1t,
                                            const float* __restrict__ Wo,
                                            u16* __restrict__ WoT) {
  __shared__ float s[32][33];
  int bid = blockIdx.x, t = threadIdx.x;
  if (bid < 16384) {
    int i = (bid * 256 + t) * 4;
    float4 v = *(const float4*)&x[i];
    ushort4 h0, h1;
    h0.x = f2h_bits(v.x); h1.x = f2h_bits((v.x - h2f_bits(h0.x)) * 4096.0f);
    h0.y = f2h_bits(v.y); h1.y = f2h_bits((v.y - h2f_bits(h0.y)) * 4096.0f);
    h0.z = f2h_bits(v.z); h1.z = f2h_bits((v.z - h2f_bits(h0.z)) * 4096.0f);
    h0.w = f2h_bits(v.w); h1.w = f2h_bits((v.w - h2f_bits(h0.w)) * 4096.0f);
    *(ushort4*)&X0[i] = h0;
    *(ushort4*)&X1[i] = h1;
  } else if (bid < 16384 + 3072) {
    int b2 = bid - 16384;
    int tx = t & 31, ty = t >> 5;
    int bk = b2 & 31, bn = b2 >> 5;
    int k0 = bk * 32, n0 = bn * 32;
#pragma unroll
    for (int i = 0; i < 4; ++i)
      s[ty + 8 * i][tx] = Wq[(size_t)(k0 + ty + 8 * i) * 3072 + n0 + tx];
    __syncthreads();
#pragma unroll
    for (int i = 0; i < 4; ++i) {
      int r = ty + 8 * i;
      int col = n0 + r;
      int h = col / 192, rem = col - h * 192;
      int cty = rem >> 6, d = rem & 63;
      int pcol = cty * 1024 + h * 64 + d;
      float v = s[tx][r];
      u16 h0 = f2h_bits(v);
      u16 h1 = f2h_bits((v - h2f_bits(h0)) * 4096.0f);
      size_t o = (size_t)pcol * 1024 + k0 + tx;
      W0t[o] = h0;
      W1t[o] = h1;
    }
  } else {
    int b3 = bid - 19456;
    int tx = t & 31, ty = t >> 5;
    int bk = b3 & 31, bn = b3 >> 5;
    int k0 = bk * 32, n0 = bn * 32;
#pragma unroll
    for (int i = 0; i < 4; ++i)
      s[ty + 8 * i][tx] = Wo[(size_t)(k0 + ty + 8 * i) * 1024 + n0 + tx];
    __syncthreads();
#pragma unroll
    for (int i = 0; i < 4; ++i) {
      int r = ty + 8 * i;
      WoT[(size_t)(n0 + r) * 1024 + k0 + tx] = f2bf(s[tx][r]);
    }
  }
}

// ---------------------------------------------------------------------------
// GEMM1a: Q/K columns, 3-pass split-f16 MFMA (f32-grade).  BK=64 = unroll-by-2
// of the round-7 proven loop (compile-time LDS bases; one barrier pair per 64
// k).  64KB LDS — free, since the kernel is register-limited to 2 blocks/CU.
// Epilogue: Q -> silu f32; K -> silu bf16 transposed Kt + ksum partials.
// ---------------------------------------------------------------------------
__global__ __launch_bounds__(256, 2) void gemm_qk_f16(
    const u16* __restrict__ X0, const u16* __restrict__ X1,
    const u16* __restrict__ W0, const u16* __restrict__ W1,
    const float* __restrict__ bq,
    float* __restrict__ Qf, u16* __restrict__ Kt, float* __restrict__ ksumP2) {
  __shared__ u16 lA0[2][128 * 32];
  __shared__ u16 lA1[2][128 * 32];
  __shared__ u16 lB0[2][128 * 32];
  __shared__ u16 lB1[2][128 * 32];   // 64KB
  int t = threadIdx.x;
  int w = t >> 6, l = t & 63;
  int wr = w >> 1, wc = w & 1;
  int lr = l & 15, lq = l >> 4;
  int mb = blockIdx.y * 128, nb = blockIdx.x * 128;
  int cty = nb >> 10;                 // 0=Q, 1=K
  f32x4 aM[4][4] = {};
  f32x4 aC[4][4] = {};

  for (int k0 = 0; k0 < 1024; k0 += 64) {
#pragma unroll
    for (int kk = 0; kk < 2; ++kk) {
#pragma unroll
      for (int it = 0; it < 2; ++it) {
        int c = t + it * 256;               // 16B chunk id, 0..511
        int r = c >> 2, j = c & 3;
        int js = j ^ ((r >> 1) & 3);        // source pre-swizzle (XOR involution)
        size_t goA = (((size_t)(mb + r)) << 10) + k0 + kk * 32 + js * 8;
        size_t goB = (((size_t)(nb + r)) << 10) + k0 + kk * 32 + js * 8;
        async_copy16(X0 + goA, (char*)lA0[kk] + (size_t)c * 16);
        async_copy16(X1 + goA, (char*)lA1[kk] + (size_t)c * 16);
        async_copy16(W0 + goB, (char*)lB0[kk] + (size_t)c * 16);
        async_copy16(W1 + goB, (char*)lB1[kk] + (size_t)c * 16);
      }
    }
    __syncthreads();
#pragma unroll
    for (int kk = 0; kk < 2; ++kk) {
      half8 b0[4], b1[4];
#pragma unroll
      for (int nn = 0; nn < 4; ++nn) {
        int rr = wc * 64 + nn * 16 + lr;
        b0[nn] = frag(lB0[kk], rr, lq);
        b1[nn] = frag(lB1[kk], rr, lq);
      }
#pragma unroll
      for (int m = 0; m < 4; ++m) {
        int rr = wr * 64 + m * 16 + lr;
        half8 a0 = frag(lA0[kk], rr, lq);
        half8 a1 = frag(lA1[kk], rr, lq);
#pragma unroll
        for (int nn = 0; nn < 4; ++nn) {
          aM[m][nn] = __builtin_amdgcn_mfma_f32_16x16x32_f16(a0, b0[nn], aM[m][nn], 0, 0, 0);
          aC[m][nn] = __builtin_amdgcn_mfma_f32_16x16x32_f16(a0, b1[nn], aC[m][nn], 0, 0, 0);
          aC[m][nn] = __builtin_amdgcn_mfma_f32_16x16x32_f16(a1, b0[nn], aC[m][nn], 0, 0, 0);
        }
      }
    }
    __syncthreads();
  }

  const float cscale = 2.44140625e-4f;    // 1/4096
  if (cty == 0) {
    // ---- Q epilogue ----
#pragma unroll
    for (int nn = 0; nn < 4; ++nn) {
      int col = nb + wc * 64 + nn * 16 + lr;
      int h = (col & 1023) >> 6, d0 = col & 63;
      float bias = bq[h * 192 + d0];
#pragma unroll
      for (int m = 0; m < 4; ++m)
#pragma unroll
        for (int j = 0; j < 4; ++j) {
          int row = mb + wr * 64 + m * 16 + lq * 4 + j;
          int b = row >> 12, n = row & 4095;
          size_t base = (((size_t)(b * 16 + h) * 4096 + n) << 6) + d0;
          float val = aM[m][nn][j] + aC[m][nn][j] * cscale + bias;
          Qf[base] = silu_f(val);
        }
    }
  } else {
    // ---- K epilogue: silu -> bf16 Kt[bh*64+d][n] + ksum partials ----
    float* red = (float*)lA0;             // 4KB reuse (post-barrier safe)
    int b = mb >> 12, nbase = mb & 4095;
#pragma unroll
    for (int nn = 0; nn < 4; ++nn) {
      int clocal = wc * 64 + nn * 16 + lr;      // 0..127
      int colk = (nb - 1024) + clocal;          // 0..1023
      int h = colk >> 6, d0 = colk & 63;
      float bias = bq[h * 192 + 64 + d0];
      size_t krow = (((size_t)(b * 16 + h) * 64 + d0) << 12) + nbase + wr * 64;
      float lsum = 0.0f;
#pragma unroll
      for (int m = 0; m < 4; ++m) {
        ushort4 pk;
        float v0 = silu_f(aM[m][nn][0] + aC[m][nn][0] * cscale + bias);
        float v1 = silu_f(aM[m][nn][1] + aC[m][nn][1] * cscale + bias);
        float v2 = silu_f(aM[m][nn][2] + aC[m][nn][2] * cscale + bias);
        float v3 = silu_f(aM[m][nn][3] + aC[m][nn][3] * cscale + bias);
        lsum += v0 + v1 + v2 + v3;
        pk.x = f2bf(v0); pk.y = f2bf(v1); pk.z = f2bf(v2); pk.w = f2bf(v3);
        *(ushort4*)&Kt[krow + m * 16 + lq * 4] = pk;
      }
      red[clocal * 8 + wr * 4 + lq] = lsum;
    }
    __syncthreads();
    if (t < 128) {
      float s = 0.0f;
#pragma unroll
      for (int c = 0; c < 8; ++c) s += red[t * 8 + c];
      int colk = (nb - 1024) + t;
      int h = colk >> 6, d0 = colk & 63;
      int rowtile = blockIdx.y & 31;
      ksumP2[(((size_t)(b * 16 + h) * 64 + d0) << 5) + rowtile] = s;
    }
  }
}

// ---------------------------------------------------------------------------
// GEMM1b: V columns, main plane only -> bf16 TRANSPOSED Vt[bh*64+e][n].
// BK=64 (unroll-by-2), 32KB LDS.  Grid (8, 128): pnb = 2048 + bx*128.
// ---------------------------------------------------------------------------
__global__ __launch_bounds__(256) void gemm_v_f16(
    const u16* __restrict__ X0, const u16* __restrict__ W0,
    const float* __restrict__ bq, u16* __restrict__ Vt) {
  __shared__ u16 lA0[2][128 * 32];
  __shared__ u16 lB0[2][128 * 32];   // 32KB
  int t = threadIdx.x;
  int w = t >> 6, l = t & 63;
  int wr = w >> 1, wc = w & 1;
  int lr = l & 15, lq = l >> 4;
  int mb = blockIdx.y * 128, nb = 2048 + blockIdx.x * 128;
  f32x4 aM[4][4] = {};

  for (int k0 = 0; k0 < 1024; k0 += 64) {
    stage_tile(X0, mb, k0, lA0[0], t);
    stage_tile(X0, mb, k0 + 32, lA0[1], t);
    stage_tile(W0, nb, k0, lB0[0], t);
    stage_tile(W0, nb, k0 + 32, lB0[1], t);
    __syncthreads();
#pragma unroll
    for (int kk = 0; kk < 2; ++kk) {
      half8 b0[4];
#pragma unroll
      for (int nn = 0; nn < 4; ++nn) b0[nn] = frag(lB0[kk], wc * 64 + nn * 16 + lr, lq);
#pragma unroll
      for (int m = 0; m < 4; ++m) {
        half8 a0 = frag(lA0[kk], wr * 64 + m * 16 + lr, lq);
#pragma unroll
        for (int nn = 0; nn < 4; ++nn)
          aM[m][nn] = __builtin_amdgcn_mfma_f32_16x16x32_f16(a0, b0[nn], aM[m][nn], 0, 0, 0);
      }
    }
    __syncthreads();
  }
  int b = mb >> 12, nbase = mb & 4095;
#pragma unroll
  for (int nn = 0; nn < 4; ++nn) {
    int colv = (nb - 2048) + wc * 64 + nn * 16 + lr;
    int h = colv >> 6, e0 = colv & 63;
    float bias = bq[h * 192 + 128 + e0];
    size_t vrow = (((size_t)(b * 16 + h) * 64 + e0) << 12) + nbase + wr * 64;
#pragma unroll
    for (int m = 0; m < 4; ++m) {
      ushort4 pk;
      pk.x = f2bf(aM[m][nn][0] + bias);
      pk.y = f2bf(aM[m][nn][1] + bias);
      pk.z = f2bf(aM[m][nn][2] + bias);
      pk.w = f2bf(aM[m][nn][3] + bias);
      *(ushort4*)&Vt[vrow + m * 16 + lq * 4] = pk;
    }
  }
}

// ---------------------------------------------------------------------------
// state_mfma: per (ch of 512 n, bh): stateP[d][e] partial = sum_n Kt[d][n]*Vt[e][n]
// via bf16 MFMA.  64x64 output, 4 waves (2x2 quadrants of 32x32), BK=32.
// ---------------------------------------------------------------------------
__global__ __launch_bounds__(256) void state_mfma(const u16* __restrict__ Kt,
                                                  const u16* __restrict__ Vt,
                                                  float* __restrict__ stateP) {
  __shared__ u16 sA[64 * 32];   // Kt rows d, 4KB
  __shared__ u16 sB[64 * 32];   // Vt rows e, 4KB
  int bh = blockIdx.y, ch = blockIdx.x, t = threadIdx.x;
  int w = t >> 6, l = t & 63;
  int wr = w >> 1, wc = w & 1;
  int lr = l & 15, lq = l >> 4;
  size_t rb = (size_t)bh << 6;           // row base (bh*64)
  f32x4 acc[2][2] = {};

  for (int n0 = ch * 512; n0 < ch * 512 + 512; n0 += 32) {
    {
      int c = t;                          // 256 chunks = whole 64x32 tile
      int r = c >> 2, j = c & 3;
      int js = j ^ ((r >> 1) & 3);
      size_t go = ((rb + (size_t)r) << 12) + n0 + js * 8;
      async_copy16(Kt + go, (char*)sA + (size_t)c * 16);
      async_copy16(Vt + go, (char*)sB + (size_t)c * 16);
    }
    __syncthreads();
    short8 bfr[2];
#pragma unroll
    for (int nn = 0; nn < 2; ++nn) bfr[nn] = frag_s(sB, wc * 32 + nn * 16 + lr, lq);
#pragma unroll
    for (int m = 0; m < 2; ++m) {
      short8 a = frag_s(sA, wr * 32 + m * 16 + lr, lq);
#pragma unroll
      for (int nn = 0; nn < 2; ++nn)
        acc[m][nn] = __builtin_amdgcn_mfma_f32_16x16x32_bf16(a, bfr[nn], acc[m][nn], 0, 0, 0);
    }
    __syncthreads();
  }

  size_t pb = ((size_t)bh * 8 + ch) * 4096;
#pragma unroll
  for (int m = 0; m < 2; ++m)
#pragma unroll
    for (int nn = 0; nn < 2; ++nn)
#pragma unroll
      for (int j = 0; j < 4; ++j) {
        int d = wr * 32 + m * 16 + lq * 4 + j;
        int e = wc * 32 + nn * 16 + lr;
        stateP[pb + (size_t)d * 64 + e] = acc[m][nn][j];
      }
}

// ---------------------------------------------------------------------------
// reduce_state2: 8 state partials -> stateT f16 [bh][e][d]; 32 ksum partials
// -> ksumF f32.
// ---------------------------------------------------------------------------
__global__ __launch_bounds__(256) void reduce_state2(const float* __restrict__ stateP,
                                                     const float* __restrict__ ksumP2,
                                                     u16* __restrict__ sTh,
                                                     float* __restrict__ ksumF) {
  int bh = blockIdx.x, t = threadIdx.x;
#pragma unroll
  for (int i = 0; i < 16; ++i) {
    int idx = t + i * 256;             // idx = d*64 + e
    float s = 0.0f;
#pragma unroll
    for (int c = 0; c < 8; ++c) s += stateP[((size_t)bh * 8 + c) * 4096 + idx];
    int d = idx >> 6, e = idx & 63;
    sTh[((size_t)bh << 12) + e * 64 + d] = f2h_bits(s);
  }
  if (t < 64) {
    float s = 0.0f;
#pragma unroll
    for (int c = 0; c < 32; ++c) s += ksumP2[(((size_t)bh * 64 + t) << 5) + c];
    ksumF[(size_t)bh * 64 + t] = s;
  }
}

// ---------------------------------------------------------------------------
// attn_mfma: den = f32 VALU (f32 Q); num = q16 @ stateT via f16 MFMA.
// out -> bf16 [B*N][1024].  (round-9 proven)
// ---------------------------------------------------------------------------
__global__ __launch_bounds__(256) void attn_mfma(const float* __restrict__ Qf,
                                                 const u16* __restrict__ sTh,
                                                 const float* __restrict__ ksumF,
                                                 u16* __restrict__ outb) {
  __shared__ u16 q16[256 * 64];
  __shared__ u16 sT[64 * 64];
  __shared__ float denp[256 * 4];
  __shared__ float den[256];
  int bh = blockIdx.y, chnk = blockIdx.x, t = threadIdx.x;
  int w = t >> 6, l = t & 63;
  int lr16 = l & 15, lq4 = l >> 4;

  {
    const u16* src = sTh + ((size_t)bh << 12);
#pragma unroll
    for (int it = 0; it < 2; ++it) {
      int c = t + it * 256;
      short8 v = *(const short8*)(src + c * 8);
      int e = c >> 3, slot = c & 7;
      *(short8*)&sT[e * 64 + ((slot ^ (e & 7)) * 8)] = v;
    }
  }
  {
    int quarter = t & 3, rbase = t >> 2;
    float4 skr[4];
#pragma unroll
    for (int i4 = 0; i4 < 4; ++i4)
      skr[i4] = *(const float4*)&ksumF[(size_t)bh * 64 + quarter * 16 + i4 * 4];
#pragma unroll
    for (int p = 0; p < 4; ++p) {
      int row = rbase + p * 64;
      int n = chnk * 256 + row;
      const float* qrow = Qf + (((size_t)bh * 4096 + n) << 6) + quarter * 16;
      float dp = 0.0f;
      u16 h[16];
#pragma unroll
      for (int i4 = 0; i4 < 4; ++i4) {
        float4 v = *(const float4*)(qrow + i4 * 4);
        dp += v.x * skr[i4].x + v.y * skr[i4].y + v.z * skr[i4].z + v.w * skr[i4].w;
        h[i4 * 4 + 0] = f2h_bits(v.x);
        h[i4 * 4 + 1] = f2h_bits(v.y);
        h[i4 * 4 + 2] = f2h_bits(v.z);
        h[i4 * 4 + 3] = f2h_bits(v.w);
      }
      denp[row * 4 + quarter] = dp;
      int s0 = (quarter * 2) ^ (row & 7);
      int s1 = (quarter * 2 + 1) ^ (row & 7);
      *(short8*)&q16[row * 64 + s0 * 8] = *(short8*)&h[0];
      *(short8*)&q16[row * 64 + s1 * 8] = *(short8*)&h[8];
    }
  }
  __syncthreads();
  den[t] = denp[t * 4] + denp[t * 4 + 1] + denp[t * 4 + 2] + denp[t * 4 + 3];
  __syncthreads();

  f32x4 acc[4][4] = {};
#pragma unroll
  for (int kh = 0; kh < 2; ++kh) {
    half8 bfr[4];
#pragma unroll
    for (int nt = 0; nt < 4; ++nt)
      bfr[nt] = frag64(sT, nt * 16 + lr16, kh * 4 + lq4);
#pragma unroll
    for (int rt = 0; rt < 4; ++rt) {
      half8 a = frag64(q16, w * 64 + rt * 16 + lr16, kh * 4 + lq4);
#pragma unroll
      for (int nt = 0; nt < 4; ++nt)
        acc[rt][nt] = __builtin_amdgcn_mfma_f32_16x16x32_f16(a, bfr[nt], acc[rt][nt], 0, 0, 0);
    }
  }

  int b = bh >> 4, hh = bh & 15;
#pragma unroll
  for (int rt = 0; rt < 4; ++rt) {
#pragma unroll
    for (int j = 0; j < 4; ++j) {
      int row = w * 64 + rt * 16 + lq4 * 4 + j;
      float rden = 1.0f / (den[row] + 1e-6f);
      int n = chnk * 256 + row;
      size_t ob = (((size_t)(b * 4096 + n)) << 10) + hh * 64;
#pragma unroll
      for (int nt = 0; nt < 4; ++nt) {
        int e = nt * 16 + lr16;
        outb[ob + e] = f2bf(acc[rt][nt][j] * rden);
      }
    }
  }
}

// ---------------------------------------------------------------------------
// GEMM2 (bf16 MFMA): d_out = out_bf16 @ W_out + b_out.  BK=64, 32KB LDS.
// ---------------------------------------------------------------------------
__global__ __launch_bounds__(256) void gemm_out(const u16* __restrict__ A,
                                                const u16* __restrict__ Bt,
                                                const float* __restrict__ bias,
                                                float* __restrict__ C) {
  __shared__ u16 lA[2][128 * 32];
  __shared__ u16 lB[2][128 * 32];   // 32KB
  int t = threadIdx.x;
  int w = t >> 6, l = t & 63;
  int wr = w >> 1, wc = w & 1;
  int lr = l & 15, lq = l >> 4;
  int mb = blockIdx.y * 128, nb = blockIdx.x * 128;
  f32x4 acc[4][4] = {};

  for (int k0 = 0; k0 < 1024; k0 += 64) {
    stage_tile(A, mb, k0, lA[0], t);
    stage_tile(A, mb, k0 + 32, lA[1], t);
    stage_tile(Bt, nb, k0, lB[0], t);
    stage_tile(Bt, nb, k0 + 32, lB[1], t);
    __syncthreads();
#pragma unroll
    for (int kk = 0; kk < 2; ++kk) {
      short8 af[4], bf[4];
#pragma unroll
      for (int m = 0; m < 4; ++m) af[m] = frag_s(lA[kk], wr * 64 + m * 16 + lr, lq);
#pragma unroll
      for (int nn = 0; nn < 4; ++nn) bf[nn] = frag_s(lB[kk], wc * 64 + nn * 16 + lr, lq);
#pragma unroll
      for (int m = 0; m < 4; ++m)
#pragma unroll
        for (int nn = 0; nn < 4; ++nn)
          acc[m][nn] = __builtin_amdgcn_mfma_f32_16x16x32_bf16(af[m], bf[nn], acc[m][nn], 0, 0, 0);
    }
    __syncthreads();
  }

#pragma unroll
  for (int m = 0; m < 4; ++m)
#pragma unroll
    for (int nn = 0; nn < 4; ++nn) {
      int col = nb + wc * 64 + nn * 16 + lr;
      float bc = bias[col];
#pragma unroll
      for (int j = 0; j < 4; ++j) {
        int row = mb + wr * 64 + m * 16 + lq * 4 + j;
        C[((size_t)row << 10) + col] = acc[m][nn][j] + bc;
      }
    }
}

// ---------------------------------------------------------------------------
// FALLBACK kernels (f32 VALU path, only if ws too small) — round-9 proven.
// ---------------------------------------------------------------------------
__global__ __launch_bounds__(256) void gemm_qkv(const float* __restrict__ X,
                                                const float* __restrict__ Wq,
                                                const float* __restrict__ bq,
                                                float* __restrict__ Qf,
                                                float* __restrict__ Kf,
                                                u16* __restrict__ Vb) {
  __shared__ float sA[16 * 132];
  __shared__ float sB[16 * 128];
  int t = threadIdx.x;
  int tm = t >> 4, tn = t & 15;
  int mb = blockIdx.y * 128, nb = blockIdx.x * 128;
  float acc[8][8] = {};

  for (int k0 = 0; k0 < 1024; k0 += 16) {
#pragma unroll
    for (int it = 0; it < 2; ++it) {
      int c = t + it * 256;
      int m = c >> 2, kc = (c & 3) * 4;
      float4 v = *(const float4*)&X[(size_t)(mb + m) * 1024 + k0 + kc];
      sA[(kc + 0) * 132 + m] = v.x;
      sA[(kc + 1) * 132 + m] = v.y;
      sA[(kc + 2) * 132 + m] = v.z;
      sA[(kc + 3) * 132 + m] = v.w;
      int kr = c >> 5, nc = (c & 31) * 4;
      async_copy16(&Wq[(size_t)(k0 + kr) * 3072 + nb + nc], (char*)sB + (size_t)c * 16);
    }
    __syncthreads();
#pragma unroll
    for (int k = 0; k < 16; ++k) {
      float4 a0 = *(const float4*)&sA[k * 132 + tm * 8];
      float4 a1 = *(const float4*)&sA[k * 132 + tm * 8 + 4];
      float4 b0 = *(const float4*)&sB[k * 128 + tn * 8];
      float4 b1 = *(const float4*)&sB[k * 128 + tn * 8 + 4];
      const float av[8] = {a0.x, a0.y, a0.z, a0.w, a1.x, a1.y, a1.z, a1.w};
      const float bv[8] = {b0.x, b0.y, b0.z, b0.w, b1.x, b1.y, b1.z, b1.w};
#pragma unroll
      for (int i = 0; i < 8; ++i)
#pragma unroll
        for (int j = 0; j < 8; ++j) acc[i][j] = fmaf(av[i], bv[j], acc[i][j]);
    }
    __syncthreads();
  }

  int c0 = nb + tn * 8;
  int h = c0 / 192, rem = c0 % 192;
  int ty = rem >> 6, d0 = rem & 63;
  float bb[8];
#pragma unroll
  for (int j = 0; j < 8; ++j) bb[j] = bq[c0 + j];
#pragma unroll
  for (int i = 0; i < 8; ++i) {
    int r = mb + tm * 8 + i;
    int b = r >> 12, n = r & 4095;
    size_t base = (((size_t)(b * 16 + h) * 4096 + n) << 6) + d0;
    if (ty == 2) {
      u16 pk[8];
#pragma unroll
      for (int j = 0; j < 8; ++j) pk[j] = f2bf(acc[i][j] + bb[j]);
      *(short8*)&Vb[base] = *(short8*)pk;
    } else {
      float* dst = (ty == 0) ? Qf : Kf;
#pragma unroll
      for (int j = 0; j < 8; ++j) dst[base + j] = silu_f(acc[i][j] + bb[j]);
    }
  }
}

__global__ __launch_bounds__(256) void state_partial(const float* __restrict__ Kf,
                                                     const u16* __restrict__ Vb,
                                                     float* __restrict__ stateP,
                                                     float* __restrict__ ksumP) {
  int bh = blockIdx.y, ch = blockIdx.x, t = threadIdx.x;
  __shared__ float sK[64 * 64];
  __shared__ u16 sV[64 * 64];
  __shared__ float sred[256];
  int n0 = ch * 512;
  size_t base = ((size_t)bh * 4096 + n0) << 6;
  float acc[4][4] = {};
  int te = t & 15, td = t >> 4;
  int kd = t & 63, kq = t >> 6;
  float kacc = 0.0f;

  for (int sc = 0; sc < 8; ++sc) {
    const float* gk = Kf + base + (size_t)sc * 64 * 64;
    const u16* gv = Vb + base + (size_t)sc * 64 * 64;
#pragma unroll
    for (int it = 0; it < 4; ++it)
      async_copy16(gk + (size_t)(t + it * 256) * 4, (char*)sK + (size_t)(t + it * 256) * 16);
#pragma unroll
    for (int it = 0; it < 2; ++it)
      async_copy16(gv + (size_t)(t + it * 256) * 8, (char*)sV + (size_t)(t + it * 256) * 16);
    __syncthreads();
#pragma unroll 4
    for (int n = 0; n < 64; ++n) {
      float4 k4 = *(const float4*)&sK[n * 64 + td * 4];
      const float ka[4] = {k4.x, k4.y, k4.z, k4.w};
      ushort4 vv = *(const ushort4*)&sV[n * 64 + te * 4];
      const float va[4] = {bf2f(vv.x), bf2f(vv.y), bf2f(vv.z), bf2f(vv.w)};
#pragma unroll
      for (int i = 0; i < 4; ++i)
#pragma unroll
        for (int j = 0; j < 4; ++j) acc[i][j] = fmaf(ka[i], va[j], acc[i][j]);
    }
#pragma unroll
    for (int i = 0; i < 16; ++i) kacc += sK[(kq * 16 + i) * 64 + kd];
    __syncthreads();
  }
  size_t pb = ((size_t)bh * 8 + ch) * 4096;
#pragma unroll
  for (int i = 0; i < 4; ++i)
#pragma unroll
    for (int j = 0; j < 4; ++j)
      stateP[pb + (size_t)(td * 4 + i) * 64 + te * 4 + j] = acc[i][j];

  sred[t] = kacc;
  __syncthreads();
  if (t < 64)
    ksumP[((size_t)bh * 8 + ch) * 64 + t] = sred[t] + sred[t + 64] + sred[t + 128] + sred[t + 192];
}

__global__ __launch_bounds__(256) void reduce_state_fb(const float* __restrict__ stateP,
                                                       const float* __restrict__ ksumP,
                                                       u16* __restrict__ sTh,
                                                       float* __restrict__ ksumF) {
  int bh = blockIdx.x, t = threadIdx.x;
#pragma unroll
  for (int i = 0; i < 16; ++i) {
    int idx = t + i * 256;
    float s = 0.0f;
#pragma unroll
    for (int c = 0; c < 8; ++c) s += stateP[((size_t)bh * 8 + c) * 4096 + idx];
    int d = idx >> 6, e = idx & 63;
    sTh[((size_t)bh << 12) + e * 64 + d] = f2h_bits(s);
  }
  if (t < 64) {
    float s = 0.0f;
#pragma unroll
    for (int c = 0; c < 8; ++c) s += ksumP[((size_t)bh * 8 + c) * 64 + t];
    ksumF[(size_t)bh * 64 + t] = s;
  }
}

// ---------------------------------------------------------------------------
extern "C" void kernel_launch(void* const* d_in, const int* in_sizes, int n_in,
                              void* d_out, int out_size, void* d_ws, size_t ws_size,
                              hipStream_t stream) {
  const float* x    = (const float*)d_in[0];
  const float* Wqkv = (const float*)d_in[1];
  const float* bqkv = (const float*)d_in[2];
  const float* Wout = (const float*)d_in[3];
  const float* bout = (const float*)d_in[4];
  float* out = (float*)d_out;

  char* w = (char*)d_ws;

  // ---- fast-path layout (~152MB) ----
  const size_t fKT  = 0;                        // Kt bf16 32MB (outb overlay)
  const size_t fVT  = fKT  + 33554432ULL;       // Vt bf16 32MB
  const size_t fSP  = fVT  + 33554432ULL;       // stateP f32 8MB
  const size_t fKP2 = fSP  + 8388608ULL;        // ksumP2 512KB
  const size_t fWT  = fKP2 + 524288ULL;         // WoutT bf16 2MB
  const size_t fST  = fWT  + 2097152ULL;        // sTh f16 512KB
  const size_t fKF  = fST  + 524288ULL;         // ksumF 16KB
  const size_t fX0  = fKF  + 16384ULL;          // X hi f16 32MB
  const size_t fX1  = fX0  + 33554432ULL;       // X lo f16 32MB
  const size_t fW0  = fX1  + 33554432ULL;       // Wqkv hi (T, permuted) 6MB
  const size_t fW1  = fW0  + 6291456ULL;        // Wqkv lo (T, permuted) 6MB
  const size_t need_fast = fW1 + 6291456ULL;    // ~152MB

  // ---- fallback layout (~108MB) ----
  const size_t bK  = 0;                         // Kf f32 64MB (outb overlay)
  const size_t bV  = bK + 67108864ULL;
  const size_t bSP = bV + 33554432ULL;
  const size_t bKP = bSP + 8388608ULL;
  const size_t bWT = bKP + 131072ULL;
  const size_t bST = bWT + 2097152ULL;
  const size_t bKF = bST + 524288ULL;
  const size_t need_base = bKF + 16384ULL;

  if (ws_size >= need_fast) {
    u16*   Kt     = (u16*)(w + fKT);
    u16*   outb   = (u16*)(w + fKT);            // overlay after Kt consumed
    u16*   Vt     = (u16*)(w + fVT);
    float* stateP = (float*)(w + fSP);
    float* ksumP2 = (float*)(w + fKP2);
    u16*   WoutT  = (u16*)(w + fWT);
    u16*   sTh    = (u16*)(w + fST);
    float* ksumF  = (float*)(w + fKF);
    u16*   X0     = (u16*)(w + fX0);
    u16*   X1     = (u16*)(w + fX1);
    u16*   W0     = (u16*)(w + fW0);
    u16*   W1     = (u16*)(w + fW1);
    float* Qf     = out;

    prep<<<dim3(20480), dim3(256), 0, stream>>>(x, X0, X1, Wqkv, W0, W1, Wout, WoutT);
    gemm_qk_f16<<<dim3(16, 128), dim3(256), 0, stream>>>(X0, X1, W0, W1, bqkv, Qf, Kt, ksumP2);
    gemm_v_f16<<<dim3(8, 128), dim3(256), 0, stream>>>(X0, W0, bqkv, Vt);
    state_mfma<<<dim3(8, 64), dim3(256), 0, stream>>>(Kt, Vt, stateP);
    reduce_state2<<<dim3(64), dim3(256), 0, stream>>>(stateP, ksumP2, sTh, ksumF);
    attn_mfma<<<dim3(16, 64), dim3(256), 0, stream>>>(Qf, sTh, ksumF, outb);
    gemm_out<<<dim3(8, 128), dim3(256), 0, stream>>>(outb, WoutT, bout, out);
  } else if (ws_size >= need_base) {
    float* Kf     = (float*)(w + bK);
    u16*   outb   = (u16*)(w + bK);
    u16*   Vb     = (u16*)(w + bV);
    float* stateP = (float*)(w + bSP);
    float* ksumP  = (float*)(w + bKP);
    u16*   WoutT  = (u16*)(w + bWT);
    u16*   sTh    = (u16*)(w + bST);
    float* ksumF  = (float*)(w + bKF);
    float* Qf     = out;

    transpose_k<<<dim3(1024), dim3(256), 0, stream>>>(Wout, WoutT, 1024, 1024);
    gemm_qkv<<<dim3(24, 128), dim3(256), 0, stream>>>(x, Wqkv, bqkv, Qf, Kf, Vb);
    state_partial<<<dim3(8, 64), dim3(256), 0, stream>>>(Kf, Vb, stateP, ksumP);
    reduce_state_fb<<<dim3(64), dim3(256), 0, stream>>>(stateP, ksumP, sTh, ksumF);
    attn_mfma<<<dim3(16, 64), dim3(256), 0, stream>>>(Qf, sTh, ksumF, outb);
    gemm_out<<<dim3(8, 128), dim3(256), 0, stream>>>(outb, WoutT, bout, out);
  }
}